// Round 3
// baseline (1534.911 us; speedup 1.0000x reference)
//
#include <hip/hip_runtime.h>

#define N_NODES    100000
#define N_EDGES    1600000
#define DIM        128
#define OUT_CH     10
#define NUM_GRAPHS 128
#define BN_EPS     1e-5f

#define BSHIFT   8
#define NB2      391
#define CAP2     5120
#define NTILES   782
#define GEMM_GRID 256

// sharded aggregation: 8 channel-shards (one per XCD), shard-major X layout,
// dynamic chunk distribution keyed on the REAL XCD id (HW_REG_XCC_ID).
#define AGG_GRID   2048
#define AGG_CHUNK  16
#define AGG_NCHUNK ((N_NODES + AGG_CHUNK - 1) / AGG_CHUNK)   // 6250

typedef __attribute__((ext_vector_type(8))) short short8;
typedef __attribute__((ext_vector_type(4))) float floatx4;

__device__ inline float bf2f(unsigned short u) {
    union { unsigned i; float f; } v; v.i = (unsigned)u << 16; return v.f;
}
__device__ inline unsigned short f2bf(float f) {
    union { float f; unsigned i; } v; v.f = f;
    return (unsigned short)((v.i + 0x8000u) >> 16);   // round-half-up, 2 ops
}

__device__ inline void async_cp16(const unsigned short* g, unsigned short* l) {
    __builtin_amdgcn_global_load_lds(
        (const __attribute__((address_space(1))) void*)g,
        (__attribute__((address_space(3))) void*)l, 16, 0, 0);
}

// ============== cvt x -> bf16 (SHARD-MAJOR), plus workspace zeroing ==============
// xb layout: [shard(8)][node][16 ch] bf16 — each shard slice is a contiguous 3.2 MB
__global__ void k_cvt_x(const float* __restrict__ x, unsigned short* __restrict__ xb,
                        int* __restrict__ gcur, float* __restrict__ stats4,
                        float* __restrict__ pooled, int* __restrict__ wcnt) {
    int t = threadIdx.x;
    if (blockIdx.x == 0) {
        for (int i = t; i < NB2 + 1; i += 256) gcur[i] = 0;
        for (int i = t; i < 4 * DIM; i += 256) stats4[i] = 0.f;
        for (int i = t; i < NUM_GRAPHS * DIM; i += 256) pooled[i] = 0.f;
        if (t < 16) wcnt[t] = 0;
    }
    int idx = blockIdx.x * 256 + t;
    float4 v = ((const float4*)x)[idx];
    ushort4 o;
    o.x = f2bf(v.x); o.y = f2bf(v.y); o.z = f2bf(v.z); o.w = f2bf(v.w);
    int node = idx >> 5, qd = idx & 31;
    int sh = qd >> 2, cc = qd & 3;
    ((ushort4*)xb)[(size_t)sh * (N_NODES * 4) + (size_t)node * 4 + cc] = o;
}

__global__ void k_prep_w(const float* __restrict__ W0, const float* __restrict__ W1,
                         const float* __restrict__ W2, const float* __restrict__ W3,
                         unsigned short* __restrict__ Wt) {
    const float* Ws[4] = {W0, W1, W2, W3};
    const float* W = Ws[blockIdx.y];
    unsigned short* o = Wt + blockIdx.y * (DIM * DIM);
    int idx = blockIdx.x * 256 + threadIdx.x;
    int n = idx >> 7, k = idx & 127;
    o[idx] = f2bf(W[k * DIM + n]);
}

// ===================== bucket partition, LDS-staged =====================
__global__ __launch_bounds__(256)
void k_bucket(const int* __restrict__ src, const int* __restrict__ dst,
              int* __restrict__ gcur, unsigned* __restrict__ pairs) {
    __shared__ int cnt[NB2 + 1];
    __shared__ int lofs[NB2 + 1];
    __shared__ int gbase[NB2 + 1];
    __shared__ int scanA[256], scanB[256];
    __shared__ int stage[8192];

    int t = threadIdx.x;
    for (int i = t; i < NB2 + 1; i += 256) cnt[i] = 0;
    __syncthreads();
    int base = blockIdx.x * 8192;
    int n_e = min(8192, N_EDGES - base);
    for (int i = t; i < n_e; i += 256)
        atomicAdd(&cnt[dst[base + i] >> BSHIFT], 1);
    __syncthreads();
    int vA = cnt[t];
    int vB = (t < NB2 - 256) ? cnt[256 + t] : 0;
    scanA[t] = vA; scanB[t] = vB;
    __syncthreads();
    for (int off = 1; off < 256; off <<= 1) {
        int tA = (t >= off) ? scanA[t - off] : 0;
        int tB = (t >= off) ? scanB[t - off] : 0;
        __syncthreads();
        scanA[t] += tA; scanB[t] += tB;
        __syncthreads();
    }
    lofs[t] = scanA[t] - vA;
    if (t < NB2 - 256) lofs[256 + t] = scanA[255] + scanB[t] - vB;
    __syncthreads();
    for (int i = t; i < NB2; i += 256) {
        gbase[i] = (cnt[i] > 0) ? atomicAdd(&gcur[i], cnt[i]) : 0;
        cnt[i] = lofs[i];
    }
    __syncthreads();
    for (int i = t; i < n_e; i += 256) {
        int d = dst[base + i];
        int b = d >> BSHIFT;
        int pos = atomicAdd(&cnt[b], 1);
        stage[pos] = (int)(((unsigned)src[base + i] << 8) | (unsigned)(d & 255));
    }
    __syncthreads();
    int w = t >> 6, lane = t & 63;
    for (int b = w; b < NB2; b += 4) {
        int len = cnt[b] - lofs[b];
        int g0  = gbase[b];
        int maxlen = CAP2 - g0; if (maxlen < 0) maxlen = 0;
        if (len > maxlen) len = maxlen;
        unsigned* dp = pairs + (size_t)b * CAP2 + g0;
        const int* sp = stage + lofs[b];
        for (int i = lane; i < len; i += 64) dp[i] = (unsigned)sp[i];
    }
}

__global__ void k_bscan(const int* __restrict__ gcur, int* __restrict__ bbase,
                        int* __restrict__ row_ptr) {
    __shared__ int sh[512];
    int t = threadIdx.x;
    int v = (t < NB2) ? min(gcur[t], CAP2) : 0;
    sh[t] = v; __syncthreads();
    for (int off = 1; off < 512; off <<= 1) {
        int tmp = (t >= off) ? sh[t - off] : 0;
        __syncthreads();
        sh[t] += tmp;
        __syncthreads();
    }
    if (t < NB2) bbase[t] = sh[t] - v;
    if (t == NB2 - 1) { bbase[NB2] = sh[t]; row_ptr[N_NODES] = sh[t]; }
}

__global__ __launch_bounds__(256)
void k_csr(const unsigned* __restrict__ pairs, const int* __restrict__ gcur,
           const int* __restrict__ bbase, int* __restrict__ row_ptr,
           int* __restrict__ col) {
    __shared__ int hist[256];
    __shared__ int cur[256];
    __shared__ int stage[CAP2];
    int bi = blockIdx.x, t = threadIdx.x;
    hist[t] = 0; __syncthreads();
    int n = min(gcur[bi], CAP2);
    const unsigned* P = pairs + (size_t)bi * CAP2;
    for (int i = t; i < n; i += 256)
        atomicAdd(&hist[P[i] & 255u], 1);
    __syncthreads();
    int self = hist[t];
    cur[t] = self; __syncthreads();
    for (int off = 1; off < 256; off <<= 1) {
        int tmp = (t >= off) ? cur[t - off] : 0;
        __syncthreads();
        cur[t] += tmp;
        __syncthreads();
    }
    int excl = cur[t] - self;
    int base = bbase[bi];
    int node = (bi << 8) + t;
    if (node < N_NODES) row_ptr[node] = base + excl;
    cur[t] = excl;
    __syncthreads();
    for (int i = t; i < n; i += 256) {
        unsigned e = P[i];
        int pos = atomicAdd(&cur[e & 255u], 1);
        stage[pos] = (int)(e >> 8);
    }
    __syncthreads();
    for (int i = t; i < n; i += 256) col[base + i] = stage[i];
}

// ============================ Aggregation ============================
// Input Xs is SHARD-MAJOR: [shard][node][16ch] bf16, each shard slice a
// contiguous 3.2 MB block that fits one XCD's 4 MB L2. shard = the block's
// actual XCD id (HW_REG_XCC_ID, wave-uniform SGPR), so affinity is exact
// regardless of dispatch mapping; node-chunks are handed out dynamically
// per shard via an atomic counter (load-balanced). Output is node-major.
// Wave layout: 16 edge-slots x 4 channel-lanes (ushort4 each), one node
// per wave pass; shfl_xor reduce over edge-slot lanes (masks 4..32).
__global__ __launch_bounds__(256)
void k_agg(const unsigned short* __restrict__ Xs,
           unsigned short* __restrict__ Out,
           const int* __restrict__ row_ptr, const int* __restrict__ col,
           int* __restrict__ wcnt) {
    __shared__ int s_chunk;
    int t = threadIdx.x;
    int w = t >> 6, lane = t & 63;
    int c = lane & 3;          // channel-lane: which ushort4 of the shard slice
    int e = lane >> 2;         // edge slot 0..15
    int shard;
    asm("s_getreg_b32 %0, hwreg(HW_REG_XCC_ID)" : "=s"(shard));
    shard &= 7;
    const ushort4* X4 = (const ushort4*)Xs + (size_t)shard * (N_NODES * 4);
    int cb = (shard << 2) + c; // ushort4 quad index within the node-major out row

    for (;;) {
        if (t == 0) s_chunk = atomicAdd(wcnt + shard, 1);
        __syncthreads();
        int chunk = s_chunk;
        __syncthreads();
        if (chunk >= AGG_NCHUNK) break;
        int n0 = chunk * AGG_CHUNK + w * 4;
        #pragma unroll
        for (int i = 0; i < 4; ++i) {
            int n = n0 + i;
            if (n >= N_NODES) break;
            int s  = row_ptr[n];
            int en = row_ptr[n + 1];
            float a0 = 0.f, a1 = 0.f, a2 = 0.f, a3 = 0.f;
            for (int p = s + e; p < en; p += 16) {
                int v = __builtin_nontemporal_load(&col[p]);
                ushort4 xv = X4[(size_t)v * 4 + c];
                a0 += bf2f(xv.x); a1 += bf2f(xv.y); a2 += bf2f(xv.z); a3 += bf2f(xv.w);
            }
            #pragma unroll
            for (int msk = 4; msk <= 32; msk <<= 1) {
                a0 += __shfl_xor(a0, msk);
                a1 += __shfl_xor(a1, msk);
                a2 += __shfl_xor(a2, msk);
                a3 += __shfl_xor(a3, msk);
            }
            if (e == 0) {
                ushort4 sv = X4[(size_t)n * 4 + c];   // self term (in-shard, cached)
                a0 += bf2f(sv.x); a1 += bf2f(sv.y); a2 += bf2f(sv.z); a3 += bf2f(sv.w);
                unsigned long long pk =
                      (unsigned long long)f2bf(a0)
                    | ((unsigned long long)f2bf(a1) << 16)
                    | ((unsigned long long)f2bf(a2) << 32)
                    | ((unsigned long long)f2bf(a3) << 48);
                __builtin_nontemporal_store(pk, (unsigned long long*)Out + (size_t)n * 32 + cb);
            }
        }
    }
}

// ================= Persistent pipelined MFMA GEMM =================
// SHARD_OUT: write C in shard-major [shard][node][16ch] (feeds next k_agg).
template<bool BN_LOAD, bool STATS, bool RELU_ST, bool SHARD_OUT>
__global__ __launch_bounds__(256)
void k_gemm(const unsigned short* __restrict__ In, unsigned short* __restrict__ Out,
            const unsigned short* __restrict__ Wt, const float* __restrict__ bias,
            const float* __restrict__ ssum_in, const float* __restrict__ ssq_in,
            const float* __restrict__ gamma, const float* __restrict__ beta,
            float* __restrict__ ssum_out, float* __restrict__ ssq_out) {
    __shared__ __align__(16) unsigned short sB[128 * 128];   // 32 KB
    __shared__ float ssc[128], ssh[128];
    __shared__ float s_sum[128], s_sq[128];

    int t = threadIdx.x;
    int w = t >> 6, lane = t & 63;
    int m = lane & 15;
    int q = lane >> 4;
    int sw = m & 7;

    #pragma unroll
    for (int u = 0; u < 8; ++u) {
        int i = (w * 8 + u) * 64 + lane;
        int n = i >> 4, p = i & 15;
        async_cp16(Wt + n * 128 + ((p ^ (n & 7)) << 3), sB + (size_t)(w * 8 + u) * 512);
    }
    if (BN_LOAD && t < 128) {
        float mn  = ssum_in[t] * (1.0f / N_NODES);
        float var = ssq_in[t] * (1.0f / N_NODES) - mn * mn;
        float inv = rsqrtf(var + BN_EPS);
        float sc  = gamma[t] * inv;
        ssc[t] = sc; ssh[t] = beta[t] - mn * sc;
    }
    if (STATS && t < 128) { s_sum[t] = 0.f; s_sq[t] = 0.f; }

    int tile = blockIdx.x;
    short8 a0[4], a1[4];
    {
        int rA0 = min(tile * 128 + w * 32 + m,      N_NODES - 1);
        int rA1 = min(tile * 128 + w * 32 + 16 + m, N_NODES - 1);
        #pragma unroll
        for (int kk = 0; kk < 4; ++kk) {
            a0[kk] = *(const short8*)(In + (size_t)rA0 * 128 + kk * 32 + q * 8);
            a1[kk] = *(const short8*)(In + (size_t)rA1 * 128 + kk * 32 + q * 8);
        }
    }
    __syncthreads();

    #pragma unroll 1
    for (; tile < NTILES; ) {
        int next = tile + GEMM_GRID;
        short8 b0[4], b1[4];
        if (next < NTILES) {
            int rN0 = min(next * 128 + w * 32 + m,      N_NODES - 1);
            int rN1 = min(next * 128 + w * 32 + 16 + m, N_NODES - 1);
            #pragma unroll
            for (int kk = 0; kk < 4; ++kk) {
                b0[kk] = *(const short8*)(In + (size_t)rN0 * 128 + kk * 32 + q * 8);
                b1[kk] = *(const short8*)(In + (size_t)rN1 * 128 + kk * 32 + q * 8);
            }
        }

        if (BN_LOAD) {
            #pragma unroll
            for (int kk = 0; kk < 4; ++kk) {
                int base = kk * 32 + q * 8;
                #pragma unroll
                for (int j = 0; j < 8; ++j) {
                    float scj = ssc[base + j], shj = ssh[base + j];
                    float f0 = fmaxf(bf2f((unsigned short)a0[kk][j]) * scj + shj, 0.f);
                    float f1 = fmaxf(bf2f((unsigned short)a1[kk][j]) * scj + shj, 0.f);
                    a0[kk][j] = (short)f2bf(f0);
                    a1[kk][j] = (short)f2bf(f1);
                }
            }
        }

        floatx4 acc[2][8] = {};
        #pragma unroll
        for (int kk = 0; kk < 4; ++kk) {
            int cp = (kk * 4 + q) ^ sw;
            #pragma unroll
            for (int c = 0; c < 8; ++c) {
                int nr = c * 16 + m;
                short8 b = *(const short8*)&sB[nr * 128 + (cp << 3)];
                acc[0][c] = __builtin_amdgcn_mfma_f32_16x16x32_bf16(b, a0[kk], acc[0][c], 0, 0, 0);
                acc[1][c] = __builtin_amdgcn_mfma_f32_16x16x32_bf16(b, a1[kk], acc[1][c], 0, 0, 0);
            }
        }

        int r0 = tile * 128;
        #pragma unroll
        for (int c = 0; c < 8; ++c) {
            int ch0 = c * 16 + q * 4;
            float4 bv = *(const float4*)(bias + ch0);
            float sr[4] = {0,0,0,0}, qr[4] = {0,0,0,0};
            #pragma unroll
            for (int h = 0; h < 2; ++h) {
                int node = r0 + w * 32 + h * 16 + m;
                float v0 = acc[h][c][0] + bv.x;
                float v1 = acc[h][c][1] + bv.y;
                float v2 = acc[h][c][2] + bv.z;
                float v3 = acc[h][c][3] + bv.w;
                if (RELU_ST) {
                    v0 = fmaxf(v0, 0.f); v1 = fmaxf(v1, 0.f);
                    v2 = fmaxf(v2, 0.f); v3 = fmaxf(v3, 0.f);
                }
                if (node < N_NODES) {
                    ushort4 o;
                    o.x = f2bf(v0); o.y = f2bf(v1); o.z = f2bf(v2); o.w = f2bf(v3);
                    if (SHARD_OUT) {
                        // shard = c (ch0>>4), quad within shard = q
                        *(ushort4*)(Out + (size_t)c * (N_NODES * 16) + (size_t)node * 16 + q * 4) = o;
                    } else {
                        *(ushort4*)(Out + (size_t)node * 128 + ch0) = o;
                    }
                    if (STATS) {
                        sr[0] += v0; sr[1] += v1; sr[2] += v2; sr[3] += v3;
                        qr[0] += v0*v0; qr[1] += v1*v1; qr[2] += v2*v2; qr[3] += v3*v3;
                    }
                }
            }
            if (STATS) {
                #pragma unroll
                for (int msk = 1; msk <= 8; msk <<= 1) {
                    #pragma unroll
                    for (int r = 0; r < 4; ++r) {
                        sr[r] += __shfl_xor(sr[r], msk);
                        qr[r] += __shfl_xor(qr[r], msk);
                    }
                }
                if (m == 0) {
                    #pragma unroll
                    for (int r = 0; r < 4; ++r) {
                        atomicAdd(&s_sum[ch0 + r], sr[r]);
                        atomicAdd(&s_sq [ch0 + r], qr[r]);
                    }
                }
            }
        }

        tile = next;
        if (tile < NTILES) {
            #pragma unroll
            for (int kk = 0; kk < 4; ++kk) { a0[kk] = b0[kk]; a1[kk] = b1[kk]; }
        }
    }

    if (STATS) {
        __syncthreads();
        if (t < 128) {
            atomicAdd(&ssum_out[t], s_sum[t]);
            atomicAdd(&ssq_out [t], s_sq[t]);
        }
    }
}

// ============== Pooling (vectorized: thread = channel-quad x subrow) ==============
#define POOL_BLOCKS 782
#define POOL_CHUNK  128
__global__ __launch_bounds__(256)
void k_pool(const unsigned short* __restrict__ h, const int* __restrict__ batch,
            float* __restrict__ pooled) {
    int t  = threadIdx.x;
    int cq = (t & 31) * 4;      // channel quad base
    int r  = t >> 5;            // subrow 0..7
    int n0 = blockIdx.x * POOL_CHUNK;
    if (n0 >= N_NODES) return;
    int n1 = min(n0 + POOL_CHUNK, N_NODES);
    float a0=0.f, a1=0.f, a2=0.f, a3=0.f;
    int g = -1;
    for (int i = n0 + r; i < n1; i += 8) {
        int gi = batch[i];
        if (gi != g) {
            if (g >= 0) {
                atomicAdd(&pooled[g * DIM + cq + 0], a0);
                atomicAdd(&pooled[g * DIM + cq + 1], a1);
                atomicAdd(&pooled[g * DIM + cq + 2], a2);
                atomicAdd(&pooled[g * DIM + cq + 3], a3);
            }
            a0 = a1 = a2 = a3 = 0.f; g = gi;
        }
        ushort4 v = *(const ushort4*)(h + (size_t)i * DIM + cq);
        a0 += bf2f(v.x); a1 += bf2f(v.y); a2 += bf2f(v.z); a3 += bf2f(v.w);
    }
    if (g >= 0) {
        atomicAdd(&pooled[g * DIM + cq + 0], a0);
        atomicAdd(&pooled[g * DIM + cq + 1], a1);
        atomicAdd(&pooled[g * DIM + cq + 2], a2);
        atomicAdd(&pooled[g * DIM + cq + 3], a3);
    }
}

// ============================ Readout (fused) ============================
__global__ void k_readout(const float* __restrict__ pooled,
                          const float* __restrict__ Wl1, const float* __restrict__ bl1,
                          const float* __restrict__ Wl2, const float* __restrict__ bl2,
                          float* __restrict__ out) {
    __shared__ float p[128], r[128];
    int g = blockIdx.x, c = threadIdx.x;
    p[c] = pooled[g * DIM + c];
    __syncthreads();
    float s = bl1[c];
    #pragma unroll 8
    for (int k = 0; k < DIM; ++k) s += p[k] * Wl1[k * DIM + c];
    r[c] = fmaxf(s, 0.f);
    __syncthreads();
    if (c < OUT_CH) {
        float s2 = bl2[c];
        #pragma unroll 8
        for (int k = 0; k < DIM; ++k) s2 += r[k] * Wl2[k * OUT_CH + c];
        out[g * OUT_CH + c] = s2;
    }
}

// ============================ Launch ============================
extern "C" void kernel_launch(void* const* d_in, const int* in_sizes, int n_in,
                              void* d_out, int out_size, void* d_ws, size_t ws_size,
                              hipStream_t stream) {
    const float* x   = (const float*)d_in[0];
    const int*   ei  = (const int*)d_in[1];
    const int*   bat = (const int*)d_in[2];
    const float* W1a = (const float*)d_in[3];
    const float* b1a = (const float*)d_in[4];
    const float* ga  = (const float*)d_in[5];
    const float* ba  = (const float*)d_in[6];
    const float* W2a = (const float*)d_in[7];
    const float* b2a = (const float*)d_in[8];
    const float* W1b = (const float*)d_in[9];
    const float* b1b = (const float*)d_in[10];
    const float* gb  = (const float*)d_in[11];
    const float* bbt = (const float*)d_in[12];
    const float* W2b = (const float*)d_in[13];
    const float* b2b = (const float*)d_in[14];
    const float* Wl1 = (const float*)d_in[15];
    const float* bl1 = (const float*)d_in[16];
    const float* Wl2 = (const float*)d_in[17];
    const float* bl2 = (const float*)d_in[18];
    float* out = (float*)d_out;

    const int* src = ei;
    const int* dst = ei + N_EDGES;

    char* w = (char*)d_ws;
    size_t off = 0;
    auto alloc = [&](size_t bytes) -> char* {
        char* p = w + off; off += (bytes + 255) & ~(size_t)255; return p;
    };
    unsigned short* xb   = (unsigned short*)alloc((size_t)N_NODES * DIM * 2);
    unsigned short* nb0  = (unsigned short*)alloc((size_t)N_NODES * DIM * 2);
    unsigned short* nb1  = (unsigned short*)alloc((size_t)N_NODES * DIM * 2);
    unsigned short* Wtb  = (unsigned short*)alloc((size_t)4 * DIM * DIM * 2);
    unsigned* pairs = (unsigned*)alloc((size_t)NB2 * CAP2 * 4);
    int*   row_ptr = (int*)  alloc((size_t)(N_NODES + 1) * 4);
    int*   col     = (int*)  alloc((size_t)N_EDGES * 4);
    int*   gcur    = (int*)  alloc((NB2 + 1) * 4);
    int*   bbase   = (int*)  alloc((NB2 + 1) * 4);
    float* stats4  = (float*)alloc((size_t)4 * DIM * 4);
    float* pooled  = (float*)alloc((size_t)NUM_GRAPHS * DIM * 4);
    int*   wcnt    = (int*)  alloc(16 * 4);
    float* ssumA = stats4, *ssqA = stats4 + DIM, *ssumB = stats4 + 2*DIM, *ssqB = stats4 + 3*DIM;

    k_cvt_x<<<(N_NODES * DIM / 4) / 256, 256, 0, stream>>>(x, xb, gcur, stats4, pooled, wcnt);
    k_prep_w<<<dim3(64, 4), 256, 0, stream>>>(W1a, W2a, W1b, W2b, Wtb);
    const unsigned short* Wt1a = Wtb;
    const unsigned short* Wt2a = Wtb + DIM * DIM;
    const unsigned short* Wt1b = Wtb + 2 * DIM * DIM;
    const unsigned short* Wt2b = Wtb + 3 * DIM * DIM;

    k_bucket<<<(N_EDGES + 8191) / 8192, 256, 0, stream>>>(src, dst, gcur, pairs);
    k_bscan<<<1, 512, 0, stream>>>(gcur, bbase, row_ptr);
    k_csr<<<NB2, 256, 0, stream>>>(pairs, gcur, bbase, row_ptr, col);

    // conv1
    k_agg<<<AGG_GRID, 256, 0, stream>>>(xb, nb0, row_ptr, col, wcnt);
    k_gemm<false, true, false, false><<<GEMM_GRID, 256, 0, stream>>>(
        nb0, nb1, Wt1a, b1a, nullptr, nullptr, nullptr, nullptr, ssumA, ssqA);
    k_gemm<true, false, true, true><<<GEMM_GRID, 256, 0, stream>>>(
        nb1, nb0, Wt2a, b2a, ssumA, ssqA, ga, ba, nullptr, nullptr);
    // conv2 (nb0 is shard-major here)
    k_agg<<<AGG_GRID, 256, 0, stream>>>(nb0, nb1, row_ptr, col, wcnt + 8);
    k_gemm<false, true, false, false><<<GEMM_GRID, 256, 0, stream>>>(
        nb1, nb0, Wt1b, b1b, nullptr, nullptr, nullptr, nullptr, ssumB, ssqB);
    k_gemm<true, false, true, false><<<GEMM_GRID, 256, 0, stream>>>(
        nb0, nb1, Wt2b, b2b, ssumB, ssqB, gb, bbt, nullptr, nullptr);
    // readout
    k_pool<<<POOL_BLOCKS, 256, 0, stream>>>(nb1, bat, pooled);
    k_readout<<<NUM_GRAPHS, 128, 0, stream>>>(pooled, Wl1, bl1, Wl2, bl2, out);
}

// Round 4
// 685.363 us; speedup vs baseline: 2.2396x; 2.2396x over previous
//
#include <hip/hip_runtime.h>

#define N_NODES    100000
#define N_EDGES    1600000
#define DIM        128
#define OUT_CH     10
#define NUM_GRAPHS 128
#define BN_EPS     1e-5f

#define BSHIFT   8
#define NB2      391
#define CAP2     5120
#define NTILES   782
#define GEMM_GRID 256

// sharded aggregation: 8 channel-shards, shard-major X layout.
// shard/rank derived STATICALLY from blockIdx (no atomics, no barriers):
// shard = blockIdx&7 rides round-robin block->XCD dispatch (XCC_ID==blockIdx%8,
// measured m09); correctness does not depend on the mapping, only L2 locality.
#define AGG_BLOCKS  2048
#define AGG_RANKS   (AGG_BLOCKS / 8)                          // 256 per shard
#define AGG_NPR     ((N_NODES + AGG_RANKS - 1) / AGG_RANKS)   // 391 nodes/rank

typedef __attribute__((ext_vector_type(8))) short short8;
typedef __attribute__((ext_vector_type(4))) float floatx4;

__device__ inline float bf2f(unsigned short u) {
    union { unsigned i; float f; } v; v.i = (unsigned)u << 16; return v.f;
}
__device__ inline unsigned short f2bf(float f) {
    union { float f; unsigned i; } v; v.f = f;
    return (unsigned short)((v.i + 0x8000u) >> 16);   // round-half-up, 2 ops
}

__device__ inline void async_cp16(const unsigned short* g, unsigned short* l) {
    __builtin_amdgcn_global_load_lds(
        (const __attribute__((address_space(1))) void*)g,
        (__attribute__((address_space(3))) void*)l, 16, 0, 0);
}

// ============== cvt x -> bf16 (SHARD-MAJOR), plus workspace zeroing ==============
// xb layout: [shard(8)][node][16 ch] bf16 — each shard slice is a contiguous 3.2 MB
__global__ void k_cvt_x(const float* __restrict__ x, unsigned short* __restrict__ xb,
                        int* __restrict__ gcur, float* __restrict__ stats4,
                        float* __restrict__ pooled) {
    int t = threadIdx.x;
    if (blockIdx.x == 0) {
        for (int i = t; i < NB2 + 1; i += 256) gcur[i] = 0;
        for (int i = t; i < 4 * DIM; i += 256) stats4[i] = 0.f;
        for (int i = t; i < NUM_GRAPHS * DIM; i += 256) pooled[i] = 0.f;
    }
    int idx = blockIdx.x * 256 + t;
    float4 v = ((const float4*)x)[idx];
    ushort4 o;
    o.x = f2bf(v.x); o.y = f2bf(v.y); o.z = f2bf(v.z); o.w = f2bf(v.w);
    int node = idx >> 5, qd = idx & 31;
    int sh = qd >> 2, cc = qd & 3;
    ((ushort4*)xb)[(size_t)sh * (N_NODES * 4) + (size_t)node * 4 + cc] = o;
}

__global__ void k_prep_w(const float* __restrict__ W0, const float* __restrict__ W1,
                         const float* __restrict__ W2, const float* __restrict__ W3,
                         unsigned short* __restrict__ Wt) {
    const float* Ws[4] = {W0, W1, W2, W3};
    const float* W = Ws[blockIdx.y];
    unsigned short* o = Wt + blockIdx.y * (DIM * DIM);
    int idx = blockIdx.x * 256 + threadIdx.x;
    int n = idx >> 7, k = idx & 127;
    o[idx] = f2bf(W[k * DIM + n]);
}

// ===================== bucket partition, LDS-staged =====================
__global__ __launch_bounds__(256)
void k_bucket(const int* __restrict__ src, const int* __restrict__ dst,
              int* __restrict__ gcur, unsigned* __restrict__ pairs) {
    __shared__ int cnt[NB2 + 1];
    __shared__ int lofs[NB2 + 1];
    __shared__ int gbase[NB2 + 1];
    __shared__ int scanA[256], scanB[256];
    __shared__ int stage[8192];

    int t = threadIdx.x;
    for (int i = t; i < NB2 + 1; i += 256) cnt[i] = 0;
    __syncthreads();
    int base = blockIdx.x * 8192;
    int n_e = min(8192, N_EDGES - base);
    for (int i = t; i < n_e; i += 256)
        atomicAdd(&cnt[dst[base + i] >> BSHIFT], 1);
    __syncthreads();
    int vA = cnt[t];
    int vB = (t < NB2 - 256) ? cnt[256 + t] : 0;
    scanA[t] = vA; scanB[t] = vB;
    __syncthreads();
    for (int off = 1; off < 256; off <<= 1) {
        int tA = (t >= off) ? scanA[t - off] : 0;
        int tB = (t >= off) ? scanB[t - off] : 0;
        __syncthreads();
        scanA[t] += tA; scanB[t] += tB;
        __syncthreads();
    }
    lofs[t] = scanA[t] - vA;
    if (t < NB2 - 256) lofs[256 + t] = scanA[255] + scanB[t] - vB;
    __syncthreads();
    for (int i = t; i < NB2; i += 256) {
        gbase[i] = (cnt[i] > 0) ? atomicAdd(&gcur[i], cnt[i]) : 0;
        cnt[i] = lofs[i];
    }
    __syncthreads();
    for (int i = t; i < n_e; i += 256) {
        int d = dst[base + i];
        int b = d >> BSHIFT;
        int pos = atomicAdd(&cnt[b], 1);
        stage[pos] = (int)(((unsigned)src[base + i] << 8) | (unsigned)(d & 255));
    }
    __syncthreads();
    int w = t >> 6, lane = t & 63;
    for (int b = w; b < NB2; b += 4) {
        int len = cnt[b] - lofs[b];
        int g0  = gbase[b];
        int maxlen = CAP2 - g0; if (maxlen < 0) maxlen = 0;
        if (len > maxlen) len = maxlen;
        unsigned* dp = pairs + (size_t)b * CAP2 + g0;
        const int* sp = stage + lofs[b];
        for (int i = lane; i < len; i += 64) dp[i] = (unsigned)sp[i];
    }
}

__global__ void k_bscan(const int* __restrict__ gcur, int* __restrict__ bbase,
                        int* __restrict__ row_ptr) {
    __shared__ int sh[512];
    int t = threadIdx.x;
    int v = (t < NB2) ? min(gcur[t], CAP2) : 0;
    sh[t] = v; __syncthreads();
    for (int off = 1; off < 512; off <<= 1) {
        int tmp = (t >= off) ? sh[t - off] : 0;
        __syncthreads();
        sh[t] += tmp;
        __syncthreads();
    }
    if (t < NB2) bbase[t] = sh[t] - v;
    if (t == NB2 - 1) { bbase[NB2] = sh[t]; row_ptr[N_NODES] = sh[t]; }
}

__global__ __launch_bounds__(256)
void k_csr(const unsigned* __restrict__ pairs, const int* __restrict__ gcur,
           const int* __restrict__ bbase, int* __restrict__ row_ptr,
           int* __restrict__ col) {
    __shared__ int hist[256];
    __shared__ int cur[256];
    __shared__ int stage[CAP2];
    int bi = blockIdx.x, t = threadIdx.x;
    hist[t] = 0; __syncthreads();
    int n = min(gcur[bi], CAP2);
    const unsigned* P = pairs + (size_t)bi * CAP2;
    for (int i = t; i < n; i += 256)
        atomicAdd(&hist[P[i] & 255u], 1);
    __syncthreads();
    int self = hist[t];
    cur[t] = self; __syncthreads();
    for (int off = 1; off < 256; off <<= 1) {
        int tmp = (t >= off) ? cur[t - off] : 0;
        __syncthreads();
        cur[t] += tmp;
        __syncthreads();
    }
    int excl = cur[t] - self;
    int base = bbase[bi];
    int node = (bi << 8) + t;
    if (node < N_NODES) row_ptr[node] = base + excl;
    cur[t] = excl;
    __syncthreads();
    for (int i = t; i < n; i += 256) {
        unsigned e = P[i];
        int pos = atomicAdd(&cur[e & 255u], 1);
        stage[pos] = (int)(e >> 8);
    }
    __syncthreads();
    for (int i = t; i < n; i += 256) col[base + i] = stage[i];
}

// ============================ Aggregation ============================
// Input Xs is SHARD-MAJOR: [shard][node][16ch] bf16 — contiguous 3.2 MB per
// shard, fits one XCD's 4 MB L2 (round-3 FETCH 648->65 MB proved this).
// Static partition: shard = blockIdx&7, rank = blockIdx>>3; rank covers a
// contiguous 391-node range. No atomics/barriers in the loop (round-3's
// 604 us was a serialized same-address far-atomic chain).
// Wave layout: 4 node-slots x 4 edge-slots x 4 channel-lanes (ushort4);
// reduce over edge-slot lane bits (masks 4,8) -> depth-2 shuffle chain.
__global__ __launch_bounds__(256)
void k_agg(const unsigned short* __restrict__ Xs,
           unsigned short* __restrict__ Out,
           const int* __restrict__ row_ptr, const int* __restrict__ col) {
    int t = threadIdx.x;
    int w = t >> 6, lane = t & 63;
    int ns = lane >> 4;          // node sub-slot 0..3
    int e  = (lane >> 2) & 3;    // edge slot 0..3
    int c  = lane & 3;           // channel ushort4 lane 0..3
    int shard = blockIdx.x & 7;
    int rank  = blockIdx.x >> 3;
    const ushort4* X4 = (const ushort4*)Xs + (size_t)shard * (N_NODES * 4);
    int cb = (shard << 2) + c;   // ull slot within the node-major out row

    int n0 = rank * AGG_NPR;
    int n1 = min(n0 + AGG_NPR, N_NODES);
    // each pass: block covers 16 nodes (4 waves x 4 node-slots)
    for (int n = n0 + w * 4 + ns; n < n1; n += 16) {
        int s  = row_ptr[n];
        int en = row_ptr[n + 1];
        float a0 = 0.f, a1 = 0.f, a2 = 0.f, a3 = 0.f;
        for (int p = s + e; p < en; p += 4) {
            int v = __builtin_nontemporal_load(&col[p]);
            ushort4 xv = X4[(size_t)v * 4 + c];
            a0 += bf2f(xv.x); a1 += bf2f(xv.y); a2 += bf2f(xv.z); a3 += bf2f(xv.w);
        }
        // reduce over the 4 edge slots (lane bits 2..3)
        a0 += __shfl_xor(a0, 4); a1 += __shfl_xor(a1, 4);
        a2 += __shfl_xor(a2, 4); a3 += __shfl_xor(a3, 4);
        a0 += __shfl_xor(a0, 8); a1 += __shfl_xor(a1, 8);
        a2 += __shfl_xor(a2, 8); a3 += __shfl_xor(a3, 8);
        if (e == 0) {
            ushort4 sv = X4[(size_t)n * 4 + c];   // self term (in-shard, cached)
            a0 += bf2f(sv.x); a1 += bf2f(sv.y); a2 += bf2f(sv.z); a3 += bf2f(sv.w);
            unsigned long long pk =
                  (unsigned long long)f2bf(a0)
                | ((unsigned long long)f2bf(a1) << 16)
                | ((unsigned long long)f2bf(a2) << 32)
                | ((unsigned long long)f2bf(a3) << 48);
            __builtin_nontemporal_store(pk, (unsigned long long*)Out + (size_t)n * 32 + cb);
        }
    }
}

// ================= Persistent pipelined MFMA GEMM =================
// SHARD_OUT: write C in shard-major [shard][node][16ch] (feeds next k_agg).
template<bool BN_LOAD, bool STATS, bool RELU_ST, bool SHARD_OUT>
__global__ __launch_bounds__(256)
void k_gemm(const unsigned short* __restrict__ In, unsigned short* __restrict__ Out,
            const unsigned short* __restrict__ Wt, const float* __restrict__ bias,
            const float* __restrict__ ssum_in, const float* __restrict__ ssq_in,
            const float* __restrict__ gamma, const float* __restrict__ beta,
            float* __restrict__ ssum_out, float* __restrict__ ssq_out) {
    __shared__ __align__(16) unsigned short sB[128 * 128];   // 32 KB
    __shared__ float ssc[128], ssh[128];
    __shared__ float s_sum[128], s_sq[128];

    int t = threadIdx.x;
    int w = t >> 6, lane = t & 63;
    int m = lane & 15;
    int q = lane >> 4;
    int sw = m & 7;

    #pragma unroll
    for (int u = 0; u < 8; ++u) {
        int i = (w * 8 + u) * 64 + lane;
        int n = i >> 4, p = i & 15;
        async_cp16(Wt + n * 128 + ((p ^ (n & 7)) << 3), sB + (size_t)(w * 8 + u) * 512);
    }
    if (BN_LOAD && t < 128) {
        float mn  = ssum_in[t] * (1.0f / N_NODES);
        float var = ssq_in[t] * (1.0f / N_NODES) - mn * mn;
        float inv = rsqrtf(var + BN_EPS);
        float sc  = gamma[t] * inv;
        ssc[t] = sc; ssh[t] = beta[t] - mn * sc;
    }
    if (STATS && t < 128) { s_sum[t] = 0.f; s_sq[t] = 0.f; }

    int tile = blockIdx.x;
    short8 a0[4], a1[4];
    {
        int rA0 = min(tile * 128 + w * 32 + m,      N_NODES - 1);
        int rA1 = min(tile * 128 + w * 32 + 16 + m, N_NODES - 1);
        #pragma unroll
        for (int kk = 0; kk < 4; ++kk) {
            a0[kk] = *(const short8*)(In + (size_t)rA0 * 128 + kk * 32 + q * 8);
            a1[kk] = *(const short8*)(In + (size_t)rA1 * 128 + kk * 32 + q * 8);
        }
    }
    __syncthreads();

    #pragma unroll 1
    for (; tile < NTILES; ) {
        int next = tile + GEMM_GRID;
        short8 b0[4], b1[4];
        if (next < NTILES) {
            int rN0 = min(next * 128 + w * 32 + m,      N_NODES - 1);
            int rN1 = min(next * 128 + w * 32 + 16 + m, N_NODES - 1);
            #pragma unroll
            for (int kk = 0; kk < 4; ++kk) {
                b0[kk] = *(const short8*)(In + (size_t)rN0 * 128 + kk * 32 + q * 8);
                b1[kk] = *(const short8*)(In + (size_t)rN1 * 128 + kk * 32 + q * 8);
            }
        }

        if (BN_LOAD) {
            #pragma unroll
            for (int kk = 0; kk < 4; ++kk) {
                int base = kk * 32 + q * 8;
                #pragma unroll
                for (int j = 0; j < 8; ++j) {
                    float scj = ssc[base + j], shj = ssh[base + j];
                    float f0 = fmaxf(bf2f((unsigned short)a0[kk][j]) * scj + shj, 0.f);
                    float f1 = fmaxf(bf2f((unsigned short)a1[kk][j]) * scj + shj, 0.f);
                    a0[kk][j] = (short)f2bf(f0);
                    a1[kk][j] = (short)f2bf(f1);
                }
            }
        }

        floatx4 acc[2][8] = {};
        #pragma unroll
        for (int kk = 0; kk < 4; ++kk) {
            int cp = (kk * 4 + q) ^ sw;
            #pragma unroll
            for (int c = 0; c < 8; ++c) {
                int nr = c * 16 + m;
                short8 b = *(const short8*)&sB[nr * 128 + (cp << 3)];
                acc[0][c] = __builtin_amdgcn_mfma_f32_16x16x32_bf16(b, a0[kk], acc[0][c], 0, 0, 0);
                acc[1][c] = __builtin_amdgcn_mfma_f32_16x16x32_bf16(b, a1[kk], acc[1][c], 0, 0, 0);
            }
        }

        int r0 = tile * 128;
        #pragma unroll
        for (int c = 0; c < 8; ++c) {
            int ch0 = c * 16 + q * 4;
            float4 bv = *(const float4*)(bias + ch0);
            float sr[4] = {0,0,0,0}, qr[4] = {0,0,0,0};
            #pragma unroll
            for (int h = 0; h < 2; ++h) {
                int node = r0 + w * 32 + h * 16 + m;
                float v0 = acc[h][c][0] + bv.x;
                float v1 = acc[h][c][1] + bv.y;
                float v2 = acc[h][c][2] + bv.z;
                float v3 = acc[h][c][3] + bv.w;
                if (RELU_ST) {
                    v0 = fmaxf(v0, 0.f); v1 = fmaxf(v1, 0.f);
                    v2 = fmaxf(v2, 0.f); v3 = fmaxf(v3, 0.f);
                }
                if (node < N_NODES) {
                    ushort4 o;
                    o.x = f2bf(v0); o.y = f2bf(v1); o.z = f2bf(v2); o.w = f2bf(v3);
                    if (SHARD_OUT) {
                        // shard = c, quad within shard = q
                        *(ushort4*)(Out + (size_t)c * (N_NODES * 16) + (size_t)node * 16 + q * 4) = o;
                    } else {
                        *(ushort4*)(Out + (size_t)node * 128 + ch0) = o;
                    }
                    if (STATS) {
                        sr[0] += v0; sr[1] += v1; sr[2] += v2; sr[3] += v3;
                        qr[0] += v0*v0; qr[1] += v1*v1; qr[2] += v2*v2; qr[3] += v3*v3;
                    }
                }
            }
            if (STATS) {
                #pragma unroll
                for (int msk = 1; msk <= 8; msk <<= 1) {
                    #pragma unroll
                    for (int r = 0; r < 4; ++r) {
                        sr[r] += __shfl_xor(sr[r], msk);
                        qr[r] += __shfl_xor(qr[r], msk);
                    }
                }
                if (m == 0) {
                    #pragma unroll
                    for (int r = 0; r < 4; ++r) {
                        atomicAdd(&s_sum[ch0 + r], sr[r]);
                        atomicAdd(&s_sq [ch0 + r], qr[r]);
                    }
                }
            }
        }

        tile = next;
        if (tile < NTILES) {
            #pragma unroll
            for (int kk = 0; kk < 4; ++kk) { a0[kk] = b0[kk]; a1[kk] = b1[kk]; }
        }
    }

    if (STATS) {
        __syncthreads();
        if (t < 128) {
            atomicAdd(&ssum_out[t], s_sum[t]);
            atomicAdd(&ssq_out [t], s_sq[t]);
        }
    }
}

// ============== Pooling (vectorized: thread = channel-quad x subrow) ==============
#define POOL_BLOCKS 782
#define POOL_CHUNK  128
__global__ __launch_bounds__(256)
void k_pool(const unsigned short* __restrict__ h, const int* __restrict__ batch,
            float* __restrict__ pooled) {
    int t  = threadIdx.x;
    int cq = (t & 31) * 4;      // channel quad base
    int r  = t >> 5;            // subrow 0..7
    int n0 = blockIdx.x * POOL_CHUNK;
    if (n0 >= N_NODES) return;
    int n1 = min(n0 + POOL_CHUNK, N_NODES);
    float a0=0.f, a1=0.f, a2=0.f, a3=0.f;
    int g = -1;
    for (int i = n0 + r; i < n1; i += 8) {
        int gi = batch[i];
        if (gi != g) {
            if (g >= 0) {
                atomicAdd(&pooled[g * DIM + cq + 0], a0);
                atomicAdd(&pooled[g * DIM + cq + 1], a1);
                atomicAdd(&pooled[g * DIM + cq + 2], a2);
                atomicAdd(&pooled[g * DIM + cq + 3], a3);
            }
            a0 = a1 = a2 = a3 = 0.f; g = gi;
        }
        ushort4 v = *(const ushort4*)(h + (size_t)i * DIM + cq);
        a0 += bf2f(v.x); a1 += bf2f(v.y); a2 += bf2f(v.z); a3 += bf2f(v.w);
    }
    if (g >= 0) {
        atomicAdd(&pooled[g * DIM + cq + 0], a0);
        atomicAdd(&pooled[g * DIM + cq + 1], a1);
        atomicAdd(&pooled[g * DIM + cq + 2], a2);
        atomicAdd(&pooled[g * DIM + cq + 3], a3);
    }
}

// ============================ Readout (fused) ============================
__global__ void k_readout(const float* __restrict__ pooled,
                          const float* __restrict__ Wl1, const float* __restrict__ bl1,
                          const float* __restrict__ Wl2, const float* __restrict__ bl2,
                          float* __restrict__ out) {
    __shared__ float p[128], r[128];
    int g = blockIdx.x, c = threadIdx.x;
    p[c] = pooled[g * DIM + c];
    __syncthreads();
    float s = bl1[c];
    #pragma unroll 8
    for (int k = 0; k < DIM; ++k) s += p[k] * Wl1[k * DIM + c];
    r[c] = fmaxf(s, 0.f);
    __syncthreads();
    if (c < OUT_CH) {
        float s2 = bl2[c];
        #pragma unroll 8
        for (int k = 0; k < DIM; ++k) s2 += r[k] * Wl2[k * OUT_CH + c];
        out[g * OUT_CH + c] = s2;
    }
}

// ============================ Launch ============================
extern "C" void kernel_launch(void* const* d_in, const int* in_sizes, int n_in,
                              void* d_out, int out_size, void* d_ws, size_t ws_size,
                              hipStream_t stream) {
    const float* x   = (const float*)d_in[0];
    const int*   ei  = (const int*)d_in[1];
    const int*   bat = (const int*)d_in[2];
    const float* W1a = (const float*)d_in[3];
    const float* b1a = (const float*)d_in[4];
    const float* ga  = (const float*)d_in[5];
    const float* ba  = (const float*)d_in[6];
    const float* W2a = (const float*)d_in[7];
    const float* b2a = (const float*)d_in[8];
    const float* W1b = (const float*)d_in[9];
    const float* b1b = (const float*)d_in[10];
    const float* gb  = (const float*)d_in[11];
    const float* bbt = (const float*)d_in[12];
    const float* W2b = (const float*)d_in[13];
    const float* b2b = (const float*)d_in[14];
    const float* Wl1 = (const float*)d_in[15];
    const float* bl1 = (const float*)d_in[16];
    const float* Wl2 = (const float*)d_in[17];
    const float* bl2 = (const float*)d_in[18];
    float* out = (float*)d_out;

    const int* src = ei;
    const int* dst = ei + N_EDGES;

    char* w = (char*)d_ws;
    size_t off = 0;
    auto alloc = [&](size_t bytes) -> char* {
        char* p = w + off; off += (bytes + 255) & ~(size_t)255; return p;
    };
    unsigned short* xb   = (unsigned short*)alloc((size_t)N_NODES * DIM * 2);
    unsigned short* nb0  = (unsigned short*)alloc((size_t)N_NODES * DIM * 2);
    unsigned short* nb1  = (unsigned short*)alloc((size_t)N_NODES * DIM * 2);
    unsigned short* Wtb  = (unsigned short*)alloc((size_t)4 * DIM * DIM * 2);
    unsigned* pairs = (unsigned*)alloc((size_t)NB2 * CAP2 * 4);
    int*   row_ptr = (int*)  alloc((size_t)(N_NODES + 1) * 4);
    int*   col     = (int*)  alloc((size_t)N_EDGES * 4);
    int*   gcur    = (int*)  alloc((NB2 + 1) * 4);
    int*   bbase   = (int*)  alloc((NB2 + 1) * 4);
    float* stats4  = (float*)alloc((size_t)4 * DIM * 4);
    float* pooled  = (float*)alloc((size_t)NUM_GRAPHS * DIM * 4);
    float* ssumA = stats4, *ssqA = stats4 + DIM, *ssumB = stats4 + 2*DIM, *ssqB = stats4 + 3*DIM;

    k_cvt_x<<<(N_NODES * DIM / 4) / 256, 256, 0, stream>>>(x, xb, gcur, stats4, pooled);
    k_prep_w<<<dim3(64, 4), 256, 0, stream>>>(W1a, W2a, W1b, W2b, Wtb);
    const unsigned short* Wt1a = Wtb;
    const unsigned short* Wt2a = Wtb + DIM * DIM;
    const unsigned short* Wt1b = Wtb + 2 * DIM * DIM;
    const unsigned short* Wt2b = Wtb + 3 * DIM * DIM;

    k_bucket<<<(N_EDGES + 8191) / 8192, 256, 0, stream>>>(src, dst, gcur, pairs);
    k_bscan<<<1, 512, 0, stream>>>(gcur, bbase, row_ptr);
    k_csr<<<NB2, 256, 0, stream>>>(pairs, gcur, bbase, row_ptr, col);

    // conv1
    k_agg<<<AGG_BLOCKS, 256, 0, stream>>>(xb, nb0, row_ptr, col);
    k_gemm<false, true, false, false><<<GEMM_GRID, 256, 0, stream>>>(
        nb0, nb1, Wt1a, b1a, nullptr, nullptr, nullptr, nullptr, ssumA, ssqA);
    k_gemm<true, false, true, true><<<GEMM_GRID, 256, 0, stream>>>(
        nb1, nb0, Wt2a, b2a, ssumA, ssqA, ga, ba, nullptr, nullptr);
    // conv2 (nb0 is shard-major here)
    k_agg<<<AGG_BLOCKS, 256, 0, stream>>>(nb0, nb1, row_ptr, col);
    k_gemm<false, true, false, false><<<GEMM_GRID, 256, 0, stream>>>(
        nb1, nb0, Wt1b, b1b, nullptr, nullptr, nullptr, nullptr, ssumB, ssqB);
    k_gemm<true, false, true, false><<<GEMM_GRID, 256, 0, stream>>>(
        nb0, nb1, Wt2b, b2b, ssumB, ssqB, gb, bbt, nullptr, nullptr);
    // readout
    k_pool<<<POOL_BLOCKS, 256, 0, stream>>>(nb1, bat, pooled);
    k_readout<<<NUM_GRAPHS, 128, 0, stream>>>(pooled, Wl1, bl1, Wl2, bl2, out);
}

// Round 5
// 522.418 us; speedup vs baseline: 2.9381x; 1.3119x over previous
//
#include <hip/hip_runtime.h>

#define N_NODES    100000
#define N_EDGES    1600000
#define DIM        128
#define OUT_CH     10
#define NUM_GRAPHS 128
#define BN_EPS     1e-5f

#define BSHIFT   8
#define NB2      391
#define CAP2     5120
#define NTILES   782
#define GEMM_GRID 256

// sharded aggregation: 8 channel-shards, shard-major X layout.
// shard/rank derived STATICALLY from blockIdx; 2048 blocks = exactly full
// residency (8 blocks/CU x 256 CU at 4 waves/block).
#define AGG_BLOCKS  2048
#define AGG_RANKS   (AGG_BLOCKS / 8)                          // 256 per shard
#define AGG_NPR     ((N_NODES + AGG_RANKS - 1) / AGG_RANKS)   // 391 nodes/rank

typedef __attribute__((ext_vector_type(8))) short short8;
typedef __attribute__((ext_vector_type(4))) float floatx4;

__device__ inline float bf2f(unsigned short u) {
    union { unsigned i; float f; } v; v.i = (unsigned)u << 16; return v.f;
}
__device__ inline unsigned short f2bf(float f) {
    union { float f; unsigned i; } v; v.f = f;
    return (unsigned short)((v.i + 0x8000u) >> 16);   // round-half-up, 2 ops
}

__device__ inline void async_cp16(const unsigned short* g, unsigned short* l) {
    __builtin_amdgcn_global_load_lds(
        (const __attribute__((address_space(1))) void*)g,
        (__attribute__((address_space(3))) void*)l, 16, 0, 0);
}

// ============== cvt x -> bf16 (SHARD-MAJOR), plus workspace zeroing ==============
// xb layout: [shard(8)][node][16 ch] bf16 — each shard slice is a contiguous 3.2 MB
__global__ void k_cvt_x(const float* __restrict__ x, unsigned short* __restrict__ xb,
                        int* __restrict__ gcur, float* __restrict__ stats4,
                        float* __restrict__ pooled) {
    int t = threadIdx.x;
    if (blockIdx.x == 0) {
        for (int i = t; i < NB2 + 1; i += 256) gcur[i] = 0;
        for (int i = t; i < 4 * DIM; i += 256) stats4[i] = 0.f;
        for (int i = t; i < NUM_GRAPHS * DIM; i += 256) pooled[i] = 0.f;
    }
    int idx = blockIdx.x * 256 + t;
    float4 v = ((const float4*)x)[idx];
    ushort4 o;
    o.x = f2bf(v.x); o.y = f2bf(v.y); o.z = f2bf(v.z); o.w = f2bf(v.w);
    int node = idx >> 5, qd = idx & 31;
    int sh = qd >> 2, cc = qd & 3;
    ((ushort4*)xb)[(size_t)sh * (N_NODES * 4) + (size_t)node * 4 + cc] = o;
}

__global__ void k_prep_w(const float* __restrict__ W0, const float* __restrict__ W1,
                         const float* __restrict__ W2, const float* __restrict__ W3,
                         unsigned short* __restrict__ Wt) {
    const float* Ws[4] = {W0, W1, W2, W3};
    const float* W = Ws[blockIdx.y];
    unsigned short* o = Wt + blockIdx.y * (DIM * DIM);
    int idx = blockIdx.x * 256 + threadIdx.x;
    int n = idx >> 7, k = idx & 127;
    o[idx] = f2bf(W[k * DIM + n]);
}

// ===================== bucket partition, LDS-staged =====================
__global__ __launch_bounds__(256)
void k_bucket(const int* __restrict__ src, const int* __restrict__ dst,
              int* __restrict__ gcur, unsigned* __restrict__ pairs) {
    __shared__ int cnt[NB2 + 1];
    __shared__ int lofs[NB2 + 1];
    __shared__ int gbase[NB2 + 1];
    __shared__ int scanA[256], scanB[256];
    __shared__ int stage[8192];

    int t = threadIdx.x;
    for (int i = t; i < NB2 + 1; i += 256) cnt[i] = 0;
    __syncthreads();
    int base = blockIdx.x * 8192;
    int n_e = min(8192, N_EDGES - base);
    for (int i = t; i < n_e; i += 256)
        atomicAdd(&cnt[dst[base + i] >> BSHIFT], 1);
    __syncthreads();
    int vA = cnt[t];
    int vB = (t < NB2 - 256) ? cnt[256 + t] : 0;
    scanA[t] = vA; scanB[t] = vB;
    __syncthreads();
    for (int off = 1; off < 256; off <<= 1) {
        int tA = (t >= off) ? scanA[t - off] : 0;
        int tB = (t >= off) ? scanB[t - off] : 0;
        __syncthreads();
        scanA[t] += tA; scanB[t] += tB;
        __syncthreads();
    }
    lofs[t] = scanA[t] - vA;
    if (t < NB2 - 256) lofs[256 + t] = scanA[255] + scanB[t] - vB;
    __syncthreads();
    for (int i = t; i < NB2; i += 256) {
        gbase[i] = (cnt[i] > 0) ? atomicAdd(&gcur[i], cnt[i]) : 0;
        cnt[i] = lofs[i];
    }
    __syncthreads();
    for (int i = t; i < n_e; i += 256) {
        int d = dst[base + i];
        int b = d >> BSHIFT;
        int pos = atomicAdd(&cnt[b], 1);
        stage[pos] = (int)(((unsigned)src[base + i] << 8) | (unsigned)(d & 255));
    }
    __syncthreads();
    int w = t >> 6, lane = t & 63;
    for (int b = w; b < NB2; b += 4) {
        int len = cnt[b] - lofs[b];
        int g0  = gbase[b];
        int maxlen = CAP2 - g0; if (maxlen < 0) maxlen = 0;
        if (len > maxlen) len = maxlen;
        unsigned* dp = pairs + (size_t)b * CAP2 + g0;
        const int* sp = stage + lofs[b];
        for (int i = lane; i < len; i += 64) dp[i] = (unsigned)sp[i];
    }
}

__global__ void k_bscan(const int* __restrict__ gcur, int* __restrict__ bbase,
                        int* __restrict__ row_ptr) {
    __shared__ int sh[512];
    int t = threadIdx.x;
    int v = (t < NB2) ? min(gcur[t], CAP2) : 0;
    sh[t] = v; __syncthreads();
    for (int off = 1; off < 512; off <<= 1) {
        int tmp = (t >= off) ? sh[t - off] : 0;
        __syncthreads();
        sh[t] += tmp;
        __syncthreads();
    }
    if (t < NB2) bbase[t] = sh[t] - v;
    if (t == NB2 - 1) { bbase[NB2] = sh[t]; row_ptr[N_NODES] = sh[t]; }
}

__global__ __launch_bounds__(256)
void k_csr(const unsigned* __restrict__ pairs, const int* __restrict__ gcur,
           const int* __restrict__ bbase, int* __restrict__ row_ptr,
           int* __restrict__ col) {
    __shared__ int hist[256];
    __shared__ int cur[256];
    __shared__ int stage[CAP2];
    int bi = blockIdx.x, t = threadIdx.x;
    hist[t] = 0; __syncthreads();
    int n = min(gcur[bi], CAP2);
    const unsigned* P = pairs + (size_t)bi * CAP2;
    for (int i = t; i < n; i += 256)
        atomicAdd(&hist[P[i] & 255u], 1);
    __syncthreads();
    int self = hist[t];
    cur[t] = self; __syncthreads();
    for (int off = 1; off < 256; off <<= 1) {
        int tmp = (t >= off) ? cur[t - off] : 0;
        __syncthreads();
        cur[t] += tmp;
        __syncthreads();
    }
    int excl = cur[t] - self;
    int base = bbase[bi];
    int node = (bi << 8) + t;
    if (node < N_NODES) row_ptr[node] = base + excl;
    cur[t] = excl;
    __syncthreads();
    for (int i = t; i < n; i += 256) {
        unsigned e = P[i];
        int pos = atomicAdd(&cur[e & 255u], 1);
        stage[pos] = (int)(e >> 8);
    }
    __syncthreads();
    for (int i = t; i < n; i += 256) col[base + i] = stage[i];
}

// ============================ Aggregation ============================
// Input Xs SHARD-MAJOR [shard][node][16ch] bf16 (3.2 MB/shard, L2-fits;
// round-3/4 FETCH proved residency). Static partition: shard=blockIdx&7,
// rank=blockIdx>>3. col/row_ptr use PLAIN loads (L3-cached; round-4's nt
// hints forced 900-cy HBM latency on the serial chain — 51 MB of FETCH).
// Latency fix: batch the col->gather dependent chain x4 per lane — 4
// independent clamped col loads, then 4 independent gathers, then
// mask-weighted FMA accumulate. One mega-iter (16 edges) covers the
// average node in ~2 latency exposures instead of ~8.
__global__ __launch_bounds__(256)
void k_agg(const unsigned short* __restrict__ Xs,
           unsigned short* __restrict__ Out,
           const int* __restrict__ row_ptr, const int* __restrict__ col) {
    int t = threadIdx.x;
    int w = t >> 6, lane = t & 63;
    int ns = lane >> 4;          // node sub-slot 0..3
    int e  = (lane >> 2) & 3;    // edge slot 0..3
    int c  = lane & 3;           // channel ushort4 lane 0..3
    int shard = blockIdx.x & 7;
    int rank  = blockIdx.x >> 3;
    const ushort4* X4 = (const ushort4*)Xs + (size_t)shard * (N_NODES * 4);
    int cb = (shard << 2) + c;   // ull slot within the node-major out row

    int n0 = rank * AGG_NPR;
    int n1 = min(n0 + AGG_NPR, N_NODES);
    // each pass: block covers 16 nodes (4 waves x 4 node-slots)
    for (int n = n0 + w * 4 + ns; n < n1; n += 16) {
        int s  = row_ptr[n];
        int en = row_ptr[n + 1];
        float a0 = 0.f, a1 = 0.f, a2 = 0.f, a3 = 0.f;
        for (int p = s + e; p < en; p += 16) {
            int p1 = p + 4, p2 = p + 8, p3 = p + 12;
            // 4 independent col loads (clamped: en-1 >= s is valid here)
            int v0 = col[p];
            int v1 = col[min(p1, en - 1)];
            int v2 = col[min(p2, en - 1)];
            int v3 = col[min(p3, en - 1)];
            // 4 independent gathers
            ushort4 x0 = X4[(size_t)v0 * 4 + c];
            ushort4 x1 = X4[(size_t)v1 * 4 + c];
            ushort4 x2 = X4[(size_t)v2 * 4 + c];
            ushort4 x3 = X4[(size_t)v3 * 4 + c];
            float m1 = (p1 < en) ? 1.f : 0.f;
            float m2 = (p2 < en) ? 1.f : 0.f;
            float m3 = (p3 < en) ? 1.f : 0.f;
            a0 += bf2f(x0.x); a1 += bf2f(x0.y); a2 += bf2f(x0.z); a3 += bf2f(x0.w);
            a0 = fmaf(m1, bf2f(x1.x), a0); a1 = fmaf(m1, bf2f(x1.y), a1);
            a2 = fmaf(m1, bf2f(x1.z), a2); a3 = fmaf(m1, bf2f(x1.w), a3);
            a0 = fmaf(m2, bf2f(x2.x), a0); a1 = fmaf(m2, bf2f(x2.y), a1);
            a2 = fmaf(m2, bf2f(x2.z), a2); a3 = fmaf(m2, bf2f(x2.w), a3);
            a0 = fmaf(m3, bf2f(x3.x), a0); a1 = fmaf(m3, bf2f(x3.y), a1);
            a2 = fmaf(m3, bf2f(x3.z), a2); a3 = fmaf(m3, bf2f(x3.w), a3);
        }
        // reduce over the 4 edge slots (lane bits 2..3)
        a0 += __shfl_xor(a0, 4); a1 += __shfl_xor(a1, 4);
        a2 += __shfl_xor(a2, 4); a3 += __shfl_xor(a3, 4);
        a0 += __shfl_xor(a0, 8); a1 += __shfl_xor(a1, 8);
        a2 += __shfl_xor(a2, 8); a3 += __shfl_xor(a3, 8);
        if (e == 0) {
            ushort4 sv = X4[(size_t)n * 4 + c];   // self term (in-shard, cached)
            a0 += bf2f(sv.x); a1 += bf2f(sv.y); a2 += bf2f(sv.z); a3 += bf2f(sv.w);
            unsigned long long pk =
                  (unsigned long long)f2bf(a0)
                | ((unsigned long long)f2bf(a1) << 16)
                | ((unsigned long long)f2bf(a2) << 32)
                | ((unsigned long long)f2bf(a3) << 48);
            __builtin_nontemporal_store(pk, (unsigned long long*)Out + (size_t)n * 32 + cb);
        }
    }
}

// ================= Persistent pipelined MFMA GEMM =================
// SHARD_OUT: write C in shard-major [shard][node][16ch] (feeds next k_agg).
template<bool BN_LOAD, bool STATS, bool RELU_ST, bool SHARD_OUT>
__global__ __launch_bounds__(256)
void k_gemm(const unsigned short* __restrict__ In, unsigned short* __restrict__ Out,
            const unsigned short* __restrict__ Wt, const float* __restrict__ bias,
            const float* __restrict__ ssum_in, const float* __restrict__ ssq_in,
            const float* __restrict__ gamma, const float* __restrict__ beta,
            float* __restrict__ ssum_out, float* __restrict__ ssq_out) {
    __shared__ __align__(16) unsigned short sB[128 * 128];   // 32 KB
    __shared__ float ssc[128], ssh[128];
    __shared__ float s_sum[128], s_sq[128];

    int t = threadIdx.x;
    int w = t >> 6, lane = t & 63;
    int m = lane & 15;
    int q = lane >> 4;
    int sw = m & 7;

    #pragma unroll
    for (int u = 0; u < 8; ++u) {
        int i = (w * 8 + u) * 64 + lane;
        int n = i >> 4, p = i & 15;
        async_cp16(Wt + n * 128 + ((p ^ (n & 7)) << 3), sB + (size_t)(w * 8 + u) * 512);
    }
    if (BN_LOAD && t < 128) {
        float mn  = ssum_in[t] * (1.0f / N_NODES);
        float var = ssq_in[t] * (1.0f / N_NODES) - mn * mn;
        float inv = rsqrtf(var + BN_EPS);
        float sc  = gamma[t] * inv;
        ssc[t] = sc; ssh[t] = beta[t] - mn * sc;
    }
    if (STATS && t < 128) { s_sum[t] = 0.f; s_sq[t] = 0.f; }

    int tile = blockIdx.x;
    short8 a0[4], a1[4];
    {
        int rA0 = min(tile * 128 + w * 32 + m,      N_NODES - 1);
        int rA1 = min(tile * 128 + w * 32 + 16 + m, N_NODES - 1);
        #pragma unroll
        for (int kk = 0; kk < 4; ++kk) {
            a0[kk] = *(const short8*)(In + (size_t)rA0 * 128 + kk * 32 + q * 8);
            a1[kk] = *(const short8*)(In + (size_t)rA1 * 128 + kk * 32 + q * 8);
        }
    }
    __syncthreads();

    #pragma unroll 1
    for (; tile < NTILES; ) {
        int next = tile + GEMM_GRID;
        short8 b0[4], b1[4];
        if (next < NTILES) {
            int rN0 = min(next * 128 + w * 32 + m,      N_NODES - 1);
            int rN1 = min(next * 128 + w * 32 + 16 + m, N_NODES - 1);
            #pragma unroll
            for (int kk = 0; kk < 4; ++kk) {
                b0[kk] = *(const short8*)(In + (size_t)rN0 * 128 + kk * 32 + q * 8);
                b1[kk] = *(const short8*)(In + (size_t)rN1 * 128 + kk * 32 + q * 8);
            }
        }

        if (BN_LOAD) {
            #pragma unroll
            for (int kk = 0; kk < 4; ++kk) {
                int base = kk * 32 + q * 8;
                #pragma unroll
                for (int j = 0; j < 8; ++j) {
                    float scj = ssc[base + j], shj = ssh[base + j];
                    float f0 = fmaxf(bf2f((unsigned short)a0[kk][j]) * scj + shj, 0.f);
                    float f1 = fmaxf(bf2f((unsigned short)a1[kk][j]) * scj + shj, 0.f);
                    a0[kk][j] = (short)f2bf(f0);
                    a1[kk][j] = (short)f2bf(f1);
                }
            }
        }

        floatx4 acc[2][8] = {};
        #pragma unroll
        for (int kk = 0; kk < 4; ++kk) {
            int cp = (kk * 4 + q) ^ sw;
            #pragma unroll
            for (int c = 0; c < 8; ++c) {
                int nr = c * 16 + m;
                short8 b = *(const short8*)&sB[nr * 128 + (cp << 3)];
                acc[0][c] = __builtin_amdgcn_mfma_f32_16x16x32_bf16(b, a0[kk], acc[0][c], 0, 0, 0);
                acc[1][c] = __builtin_amdgcn_mfma_f32_16x16x32_bf16(b, a1[kk], acc[1][c], 0, 0, 0);
            }
        }

        int r0 = tile * 128;
        #pragma unroll
        for (int c = 0; c < 8; ++c) {
            int ch0 = c * 16 + q * 4;
            float4 bv = *(const float4*)(bias + ch0);
            float sr[4] = {0,0,0,0}, qr[4] = {0,0,0,0};
            #pragma unroll
            for (int h = 0; h < 2; ++h) {
                int node = r0 + w * 32 + h * 16 + m;
                float v0 = acc[h][c][0] + bv.x;
                float v1 = acc[h][c][1] + bv.y;
                float v2 = acc[h][c][2] + bv.z;
                float v3 = acc[h][c][3] + bv.w;
                if (RELU_ST) {
                    v0 = fmaxf(v0, 0.f); v1 = fmaxf(v1, 0.f);
                    v2 = fmaxf(v2, 0.f); v3 = fmaxf(v3, 0.f);
                }
                if (node < N_NODES) {
                    ushort4 o;
                    o.x = f2bf(v0); o.y = f2bf(v1); o.z = f2bf(v2); o.w = f2bf(v3);
                    if (SHARD_OUT) {
                        // shard = c, quad within shard = q
                        *(ushort4*)(Out + (size_t)c * (N_NODES * 16) + (size_t)node * 16 + q * 4) = o;
                    } else {
                        *(ushort4*)(Out + (size_t)node * 128 + ch0) = o;
                    }
                    if (STATS) {
                        sr[0] += v0; sr[1] += v1; sr[2] += v2; sr[3] += v3;
                        qr[0] += v0*v0; qr[1] += v1*v1; qr[2] += v2*v2; qr[3] += v3*v3;
                    }
                }
            }
            if (STATS) {
                #pragma unroll
                for (int msk = 1; msk <= 8; msk <<= 1) {
                    #pragma unroll
                    for (int r = 0; r < 4; ++r) {
                        sr[r] += __shfl_xor(sr[r], msk);
                        qr[r] += __shfl_xor(qr[r], msk);
                    }
                }
                if (m == 0) {
                    #pragma unroll
                    for (int r = 0; r < 4; ++r) {
                        atomicAdd(&s_sum[ch0 + r], sr[r]);
                        atomicAdd(&s_sq [ch0 + r], qr[r]);
                    }
                }
            }
        }

        tile = next;
        if (tile < NTILES) {
            #pragma unroll
            for (int kk = 0; kk < 4; ++kk) { a0[kk] = b0[kk]; a1[kk] = b1[kk]; }
        }
    }

    if (STATS) {
        __syncthreads();
        if (t < 128) {
            atomicAdd(&ssum_out[t], s_sum[t]);
            atomicAdd(&ssq_out [t], s_sq[t]);
        }
    }
}

// ============== Pooling (vectorized: thread = channel-quad x subrow) ==============
#define POOL_BLOCKS 782
#define POOL_CHUNK  128
__global__ __launch_bounds__(256)
void k_pool(const unsigned short* __restrict__ h, const int* __restrict__ batch,
            float* __restrict__ pooled) {
    int t  = threadIdx.x;
    int cq = (t & 31) * 4;      // channel quad base
    int r  = t >> 5;            // subrow 0..7
    int n0 = blockIdx.x * POOL_CHUNK;
    if (n0 >= N_NODES) return;
    int n1 = min(n0 + POOL_CHUNK, N_NODES);
    float a0=0.f, a1=0.f, a2=0.f, a3=0.f;
    int g = -1;
    for (int i = n0 + r; i < n1; i += 8) {
        int gi = batch[i];
        if (gi != g) {
            if (g >= 0) {
                atomicAdd(&pooled[g * DIM + cq + 0], a0);
                atomicAdd(&pooled[g * DIM + cq + 1], a1);
                atomicAdd(&pooled[g * DIM + cq + 2], a2);
                atomicAdd(&pooled[g * DIM + cq + 3], a3);
            }
            a0 = a1 = a2 = a3 = 0.f; g = gi;
        }
        ushort4 v = *(const ushort4*)(h + (size_t)i * DIM + cq);
        a0 += bf2f(v.x); a1 += bf2f(v.y); a2 += bf2f(v.z); a3 += bf2f(v.w);
    }
    if (g >= 0) {
        atomicAdd(&pooled[g * DIM + cq + 0], a0);
        atomicAdd(&pooled[g * DIM + cq + 1], a1);
        atomicAdd(&pooled[g * DIM + cq + 2], a2);
        atomicAdd(&pooled[g * DIM + cq + 3], a3);
    }
}

// ============================ Readout (fused) ============================
__global__ void k_readout(const float* __restrict__ pooled,
                          const float* __restrict__ Wl1, const float* __restrict__ bl1,
                          const float* __restrict__ Wl2, const float* __restrict__ bl2,
                          float* __restrict__ out) {
    __shared__ float p[128], r[128];
    int g = blockIdx.x, c = threadIdx.x;
    p[c] = pooled[g * DIM + c];
    __syncthreads();
    float s = bl1[c];
    #pragma unroll 8
    for (int k = 0; k < DIM; ++k) s += p[k] * Wl1[k * DIM + c];
    r[c] = fmaxf(s, 0.f);
    __syncthreads();
    if (c < OUT_CH) {
        float s2 = bl2[c];
        #pragma unroll 8
        for (int k = 0; k < DIM; ++k) s2 += r[k] * Wl2[k * OUT_CH + c];
        out[g * OUT_CH + c] = s2;
    }
}

// ============================ Launch ============================
extern "C" void kernel_launch(void* const* d_in, const int* in_sizes, int n_in,
                              void* d_out, int out_size, void* d_ws, size_t ws_size,
                              hipStream_t stream) {
    const float* x   = (const float*)d_in[0];
    const int*   ei  = (const int*)d_in[1];
    const int*   bat = (const int*)d_in[2];
    const float* W1a = (const float*)d_in[3];
    const float* b1a = (const float*)d_in[4];
    const float* ga  = (const float*)d_in[5];
    const float* ba  = (const float*)d_in[6];
    const float* W2a = (const float*)d_in[7];
    const float* b2a = (const float*)d_in[8];
    const float* W1b = (const float*)d_in[9];
    const float* b1b = (const float*)d_in[10];
    const float* gb  = (const float*)d_in[11];
    const float* bbt = (const float*)d_in[12];
    const float* W2b = (const float*)d_in[13];
    const float* b2b = (const float*)d_in[14];
    const float* Wl1 = (const float*)d_in[15];
    const float* bl1 = (const float*)d_in[16];
    const float* Wl2 = (const float*)d_in[17];
    const float* bl2 = (const float*)d_in[18];
    float* out = (float*)d_out;

    const int* src = ei;
    const int* dst = ei + N_EDGES;

    char* w = (char*)d_ws;
    size_t off = 0;
    auto alloc = [&](size_t bytes) -> char* {
        char* p = w + off; off += (bytes + 255) & ~(size_t)255; return p;
    };
    unsigned short* xb   = (unsigned short*)alloc((size_t)N_NODES * DIM * 2);
    unsigned short* nb0  = (unsigned short*)alloc((size_t)N_NODES * DIM * 2);
    unsigned short* nb1  = (unsigned short*)alloc((size_t)N_NODES * DIM * 2);
    unsigned short* Wtb  = (unsigned short*)alloc((size_t)4 * DIM * DIM * 2);
    unsigned* pairs = (unsigned*)alloc((size_t)NB2 * CAP2 * 4);
    int*   row_ptr = (int*)  alloc((size_t)(N_NODES + 1) * 4);
    int*   col     = (int*)  alloc((size_t)N_EDGES * 4);
    int*   gcur    = (int*)  alloc((NB2 + 1) * 4);
    int*   bbase   = (int*)  alloc((NB2 + 1) * 4);
    float* stats4  = (float*)alloc((size_t)4 * DIM * 4);
    float* pooled  = (float*)alloc((size_t)NUM_GRAPHS * DIM * 4);
    float* ssumA = stats4, *ssqA = stats4 + DIM, *ssumB = stats4 + 2*DIM, *ssqB = stats4 + 3*DIM;

    k_cvt_x<<<(N_NODES * DIM / 4) / 256, 256, 0, stream>>>(x, xb, gcur, stats4, pooled);
    k_prep_w<<<dim3(64, 4), 256, 0, stream>>>(W1a, W2a, W1b, W2b, Wtb);
    const unsigned short* Wt1a = Wtb;
    const unsigned short* Wt2a = Wtb + DIM * DIM;
    const unsigned short* Wt1b = Wtb + 2 * DIM * DIM;
    const unsigned short* Wt2b = Wtb + 3 * DIM * DIM;

    k_bucket<<<(N_EDGES + 8191) / 8192, 256, 0, stream>>>(src, dst, gcur, pairs);
    k_bscan<<<1, 512, 0, stream>>>(gcur, bbase, row_ptr);
    k_csr<<<NB2, 256, 0, stream>>>(pairs, gcur, bbase, row_ptr, col);

    // conv1
    k_agg<<<AGG_BLOCKS, 256, 0, stream>>>(xb, nb0, row_ptr, col);
    k_gemm<false, true, false, false><<<GEMM_GRID, 256, 0, stream>>>(
        nb0, nb1, Wt1a, b1a, nullptr, nullptr, nullptr, nullptr, ssumA, ssqA);
    k_gemm<true, false, true, true><<<GEMM_GRID, 256, 0, stream>>>(
        nb1, nb0, Wt2a, b2a, ssumA, ssqA, ga, ba, nullptr, nullptr);
    // conv2 (nb0 is shard-major here)
    k_agg<<<AGG_BLOCKS, 256, 0, stream>>>(nb0, nb1, row_ptr, col);
    k_gemm<false, true, false, false><<<GEMM_GRID, 256, 0, stream>>>(
        nb1, nb0, Wt1b, b1b, nullptr, nullptr, nullptr, nullptr, ssumB, ssqB);
    k_gemm<true, false, true, false><<<GEMM_GRID, 256, 0, stream>>>(
        nb0, nb1, Wt2b, b2b, ssumB, ssqB, gb, bbt, nullptr, nullptr);
    // readout
    k_pool<<<POOL_BLOCKS, 256, 0, stream>>>(nb1, bat, pooled);
    k_readout<<<NUM_GRAPHS, 128, 0, stream>>>(pooled, Wl1, bl1, Wl2, bl2, out);
}

// Round 6
// 489.481 us; speedup vs baseline: 3.1358x; 1.0673x over previous
//
#include <hip/hip_runtime.h>

#define N_NODES    100000
#define N_EDGES    1600000
#define DIM        128
#define OUT_CH     10
#define NUM_GRAPHS 128
#define BN_EPS     1e-5f

#define BSHIFT   8
#define NB2      391
#define CAP2     5120
#define NTILES   782
#define GEMM_GRID 256

// sharded aggregation: 8 channel-shards, shard-major X layout.
#define AGG_BLOCKS  2048
#define AGG_RANKS   (AGG_BLOCKS / 8)                          // 256 per shard
#define AGG_NPR     ((N_NODES + AGG_RANKS - 1) / AGG_RANKS)   // 391 nodes/rank

typedef __attribute__((ext_vector_type(8))) short short8;
typedef __attribute__((ext_vector_type(4))) float floatx4;

__device__ inline float bf2f(unsigned short u) {
    union { unsigned i; float f; } v; v.i = (unsigned)u << 16; return v.f;
}
__device__ inline unsigned short f2bf(float f) {
    union { float f; unsigned i; } v; v.f = f;
    return (unsigned short)((v.i + 0x8000u) >> 16);   // round-half-up, 2 ops
}

__device__ inline void async_cp16(const unsigned short* g, unsigned short* l) {
    __builtin_amdgcn_global_load_lds(
        (const __attribute__((address_space(1))) void*)g,
        (__attribute__((address_space(3))) void*)l, 16, 0, 0);
}

// ============== cvt x -> bf16 (SHARD-MAJOR), plus workspace zeroing ==============
// xb layout: [shard(8)][node][16 ch] bf16 — each shard slice is a contiguous 3.2 MB
__global__ void k_cvt_x(const float* __restrict__ x, unsigned short* __restrict__ xb,
                        int* __restrict__ gcur, float* __restrict__ stats4,
                        float* __restrict__ pooled) {
    int t = threadIdx.x;
    if (blockIdx.x == 0) {
        for (int i = t; i < NB2 + 1; i += 256) gcur[i] = 0;
        for (int i = t; i < 4 * DIM; i += 256) stats4[i] = 0.f;
        for (int i = t; i < NUM_GRAPHS * DIM; i += 256) pooled[i] = 0.f;
    }
    int idx = blockIdx.x * 256 + t;
    float4 v = ((const float4*)x)[idx];
    ushort4 o;
    o.x = f2bf(v.x); o.y = f2bf(v.y); o.z = f2bf(v.z); o.w = f2bf(v.w);
    int node = idx >> 5, qd = idx & 31;
    int sh = qd >> 2, cc = qd & 3;
    ((ushort4*)xb)[(size_t)sh * (N_NODES * 4) + (size_t)node * 4 + cc] = o;
}

__global__ void k_prep_w(const float* __restrict__ W0, const float* __restrict__ W1,
                         const float* __restrict__ W2, const float* __restrict__ W3,
                         unsigned short* __restrict__ Wt) {
    const float* Ws[4] = {W0, W1, W2, W3};
    const float* W = Ws[blockIdx.y];
    unsigned short* o = Wt + blockIdx.y * (DIM * DIM);
    int idx = blockIdx.x * 256 + threadIdx.x;
    int n = idx >> 7, k = idx & 127;
    o[idx] = f2bf(W[k * DIM + n]);
}

// ===================== bucket partition, LDS-staged =====================
__global__ __launch_bounds__(256)
void k_bucket(const int* __restrict__ src, const int* __restrict__ dst,
              int* __restrict__ gcur, unsigned* __restrict__ pairs) {
    __shared__ int cnt[NB2 + 1];
    __shared__ int lofs[NB2 + 1];
    __shared__ int gbase[NB2 + 1];
    __shared__ int scanA[256], scanB[256];
    __shared__ int stage[8192];

    int t = threadIdx.x;
    for (int i = t; i < NB2 + 1; i += 256) cnt[i] = 0;
    __syncthreads();
    int base = blockIdx.x * 8192;
    int n_e = min(8192, N_EDGES - base);
    for (int i = t; i < n_e; i += 256)
        atomicAdd(&cnt[dst[base + i] >> BSHIFT], 1);
    __syncthreads();
    int vA = cnt[t];
    int vB = (t < NB2 - 256) ? cnt[256 + t] : 0;
    scanA[t] = vA; scanB[t] = vB;
    __syncthreads();
    for (int off = 1; off < 256; off <<= 1) {
        int tA = (t >= off) ? scanA[t - off] : 0;
        int tB = (t >= off) ? scanB[t - off] : 0;
        __syncthreads();
        scanA[t] += tA; scanB[t] += tB;
        __syncthreads();
    }
    lofs[t] = scanA[t] - vA;
    if (t < NB2 - 256) lofs[256 + t] = scanA[255] + scanB[t] - vB;
    __syncthreads();
    for (int i = t; i < NB2; i += 256) {
        gbase[i] = (cnt[i] > 0) ? atomicAdd(&gcur[i], cnt[i]) : 0;
        cnt[i] = lofs[i];
    }
    __syncthreads();
    for (int i = t; i < n_e; i += 256) {
        int d = dst[base + i];
        int b = d >> BSHIFT;
        int pos = atomicAdd(&cnt[b], 1);
        stage[pos] = (int)(((unsigned)src[base + i] << 8) | (unsigned)(d & 255));
    }
    __syncthreads();
    int w = t >> 6, lane = t & 63;
    for (int b = w; b < NB2; b += 4) {
        int len = cnt[b] - lofs[b];
        int g0  = gbase[b];
        int maxlen = CAP2 - g0; if (maxlen < 0) maxlen = 0;
        if (len > maxlen) len = maxlen;
        unsigned* dp = pairs + (size_t)b * CAP2 + g0;
        const int* sp = stage + lofs[b];
        for (int i = lane; i < len; i += 64) dp[i] = (unsigned)sp[i];
    }
}

__global__ void k_bscan(const int* __restrict__ gcur, int* __restrict__ bbase,
                        int* __restrict__ row_ptr) {
    __shared__ int sh[512];
    int t = threadIdx.x;
    int v = (t < NB2) ? min(gcur[t], CAP2) : 0;
    sh[t] = v; __syncthreads();
    for (int off = 1; off < 512; off <<= 1) {
        int tmp = (t >= off) ? sh[t - off] : 0;
        __syncthreads();
        sh[t] += tmp;
        __syncthreads();
    }
    if (t < NB2) bbase[t] = sh[t] - v;
    if (t == NB2 - 1) { bbase[NB2] = sh[t]; row_ptr[N_NODES] = sh[t]; }
}

// col entries are PRE-SCALED byte offsets (src_node << 5 = offset of the 32 B
// shard-row) so k_agg's gather is SGPR-base + 32-bit-voffset with zero
// per-lane address arithmetic.
__global__ __launch_bounds__(256)
void k_csr(const unsigned* __restrict__ pairs, const int* __restrict__ gcur,
           const int* __restrict__ bbase, int* __restrict__ row_ptr,
           int* __restrict__ col) {
    __shared__ int hist[256];
    __shared__ int cur[256];
    __shared__ int stage[CAP2];
    int bi = blockIdx.x, t = threadIdx.x;
    hist[t] = 0; __syncthreads();
    int n = min(gcur[bi], CAP2);
    const unsigned* P = pairs + (size_t)bi * CAP2;
    for (int i = t; i < n; i += 256)
        atomicAdd(&hist[P[i] & 255u], 1);
    __syncthreads();
    int self = hist[t];
    cur[t] = self; __syncthreads();
    for (int off = 1; off < 256; off <<= 1) {
        int tmp = (t >= off) ? cur[t - off] : 0;
        __syncthreads();
        cur[t] += tmp;
        __syncthreads();
    }
    int excl = cur[t] - self;
    int base = bbase[bi];
    int node = (bi << 8) + t;
    if (node < N_NODES) row_ptr[node] = base + excl;
    cur[t] = excl;
    __syncthreads();
    for (int i = t; i < n; i += 256) {
        unsigned e = P[i];
        int pos = atomicAdd(&cur[e & 255u], 1);
        stage[pos] = (int)((e >> 8) << 5);   // byte offset of 32 B shard-row
    }
    __syncthreads();
    for (int i = t; i < n; i += 256) col[base + i] = stage[i];
}

// ============================ Aggregation ============================
// Xs SHARD-MAJOR [shard][node][16ch] bf16 (3.2 MB/shard, L2-resident —
// FETCH 47 MB proved). Static partition: shard=blockIdx&7, rank=blockIdx>>3.
// VALU diet (round-5 was issue-bound at 48% busy):
//  - col holds pre-scaled byte offsets -> gather = SGPR base + 32b voffset
//  - 16 B short8 gathers: 2 ch-lanes cover the 32 B shard row
//  - wave = 4 node-slots x 8 edge-slots x 2 ch-lanes; batch-2 (stride 8)
//    keeps two independent col->gather chains in flight; one sweep = 16
//    edges = avg degree. Reduce over edge-slots: shfl_xor 2,4,8.
__global__ __launch_bounds__(256)
void k_agg(const unsigned short* __restrict__ Xs,
           unsigned short* __restrict__ Out,
           const int* __restrict__ row_ptr, const int* __restrict__ col) {
    int t = threadIdx.x;
    int w = t >> 6, lane = t & 63;
    int ns = lane >> 4;          // node sub-slot 0..3
    int e  = (lane >> 1) & 7;    // edge slot 0..7
    int c  = lane & 1;           // which 16 B half of the 32 B shard row
    int shard = blockIdx.x & 7;
    int rank  = blockIdx.x >> 3;
    const char* Xb = (const char*)Xs + (size_t)shard * (N_NODES * 32);
    char* OutB = (char*)Out;
    int ch16 = c << 4;

    int n0 = rank * AGG_NPR;
    int n1 = min(n0 + AGG_NPR, N_NODES);
    for (int n = n0 + w * 4 + ns; n < n1; n += 16) {
        int s  = row_ptr[n];
        int en = row_ptr[n + 1];
        float a0=0.f,a1=0.f,a2=0.f,a3=0.f,a4=0.f,a5=0.f,a6=0.f,a7=0.f;
        for (int p = s + e; p < en; p += 16) {
            int off0 = col[p];                    // valid: p < en
            int p1 = p + 8;
            int off1 = col[min(p1, en - 1)];      // clamped, masked below
            short8 x0 = *(const short8*)(Xb + off0 + ch16);
            short8 x1 = *(const short8*)(Xb + off1 + ch16);
            float m1 = (p1 < en) ? 1.f : 0.f;
            a0 += bf2f((unsigned short)x0[0]); a1 += bf2f((unsigned short)x0[1]);
            a2 += bf2f((unsigned short)x0[2]); a3 += bf2f((unsigned short)x0[3]);
            a4 += bf2f((unsigned short)x0[4]); a5 += bf2f((unsigned short)x0[5]);
            a6 += bf2f((unsigned short)x0[6]); a7 += bf2f((unsigned short)x0[7]);
            a0 = fmaf(m1, bf2f((unsigned short)x1[0]), a0);
            a1 = fmaf(m1, bf2f((unsigned short)x1[1]), a1);
            a2 = fmaf(m1, bf2f((unsigned short)x1[2]), a2);
            a3 = fmaf(m1, bf2f((unsigned short)x1[3]), a3);
            a4 = fmaf(m1, bf2f((unsigned short)x1[4]), a4);
            a5 = fmaf(m1, bf2f((unsigned short)x1[5]), a5);
            a6 = fmaf(m1, bf2f((unsigned short)x1[6]), a6);
            a7 = fmaf(m1, bf2f((unsigned short)x1[7]), a7);
        }
        // reduce over the 8 edge slots (lane bits 1..3)
        #pragma unroll
        for (int msk = 2; msk <= 8; msk <<= 1) {
            a0 += __shfl_xor(a0, msk); a1 += __shfl_xor(a1, msk);
            a2 += __shfl_xor(a2, msk); a3 += __shfl_xor(a3, msk);
            a4 += __shfl_xor(a4, msk); a5 += __shfl_xor(a5, msk);
            a6 += __shfl_xor(a6, msk); a7 += __shfl_xor(a7, msk);
        }
        if ((lane & 14) == 0) {   // e == 0; both c lanes store their 16 B half
            short8 sv = *(const short8*)(Xb + (size_t)n * 32 + ch16);   // self term
            a0 += bf2f((unsigned short)sv[0]); a1 += bf2f((unsigned short)sv[1]);
            a2 += bf2f((unsigned short)sv[2]); a3 += bf2f((unsigned short)sv[3]);
            a4 += bf2f((unsigned short)sv[4]); a5 += bf2f((unsigned short)sv[5]);
            a6 += bf2f((unsigned short)sv[6]); a7 += bf2f((unsigned short)sv[7]);
            short8 r;
            r[0] = (short)f2bf(a0); r[1] = (short)f2bf(a1);
            r[2] = (short)f2bf(a2); r[3] = (short)f2bf(a3);
            r[4] = (short)f2bf(a4); r[5] = (short)f2bf(a5);
            r[6] = (short)f2bf(a6); r[7] = (short)f2bf(a7);
            __builtin_nontemporal_store(r,
                (short8*)(OutB + (size_t)n * 256 + (shard << 5) + ch16));
        }
    }
}

// ================= Persistent pipelined MFMA GEMM =================
// SHARD_OUT: write C in shard-major [shard][node][16ch] (feeds next k_agg).
template<bool BN_LOAD, bool STATS, bool RELU_ST, bool SHARD_OUT>
__global__ __launch_bounds__(256)
void k_gemm(const unsigned short* __restrict__ In, unsigned short* __restrict__ Out,
            const unsigned short* __restrict__ Wt, const float* __restrict__ bias,
            const float* __restrict__ ssum_in, const float* __restrict__ ssq_in,
            const float* __restrict__ gamma, const float* __restrict__ beta,
            float* __restrict__ ssum_out, float* __restrict__ ssq_out) {
    __shared__ __align__(16) unsigned short sB[128 * 128];   // 32 KB
    __shared__ float ssc[128], ssh[128];
    __shared__ float s_sum[128], s_sq[128];

    int t = threadIdx.x;
    int w = t >> 6, lane = t & 63;
    int m = lane & 15;
    int q = lane >> 4;
    int sw = m & 7;

    #pragma unroll
    for (int u = 0; u < 8; ++u) {
        int i = (w * 8 + u) * 64 + lane;
        int n = i >> 4, p = i & 15;
        async_cp16(Wt + n * 128 + ((p ^ (n & 7)) << 3), sB + (size_t)(w * 8 + u) * 512);
    }
    if (BN_LOAD && t < 128) {
        float mn  = ssum_in[t] * (1.0f / N_NODES);
        float var = ssq_in[t] * (1.0f / N_NODES) - mn * mn;
        float inv = rsqrtf(var + BN_EPS);
        float sc  = gamma[t] * inv;
        ssc[t] = sc; ssh[t] = beta[t] - mn * sc;
    }
    if (STATS && t < 128) { s_sum[t] = 0.f; s_sq[t] = 0.f; }

    int tile = blockIdx.x;
    short8 a0[4], a1[4];
    {
        int rA0 = min(tile * 128 + w * 32 + m,      N_NODES - 1);
        int rA1 = min(tile * 128 + w * 32 + 16 + m, N_NODES - 1);
        #pragma unroll
        for (int kk = 0; kk < 4; ++kk) {
            a0[kk] = *(const short8*)(In + (size_t)rA0 * 128 + kk * 32 + q * 8);
            a1[kk] = *(const short8*)(In + (size_t)rA1 * 128 + kk * 32 + q * 8);
        }
    }
    __syncthreads();

    #pragma unroll 1
    for (; tile < NTILES; ) {
        int next = tile + GEMM_GRID;
        short8 b0[4], b1[4];
        if (next < NTILES) {
            int rN0 = min(next * 128 + w * 32 + m,      N_NODES - 1);
            int rN1 = min(next * 128 + w * 32 + 16 + m, N_NODES - 1);
            #pragma unroll
            for (int kk = 0; kk < 4; ++kk) {
                b0[kk] = *(const short8*)(In + (size_t)rN0 * 128 + kk * 32 + q * 8);
                b1[kk] = *(const short8*)(In + (size_t)rN1 * 128 + kk * 32 + q * 8);
            }
        }

        if (BN_LOAD) {
            #pragma unroll
            for (int kk = 0; kk < 4; ++kk) {
                int base = kk * 32 + q * 8;
                #pragma unroll
                for (int j = 0; j < 8; ++j) {
                    float scj = ssc[base + j], shj = ssh[base + j];
                    float f0 = fmaxf(bf2f((unsigned short)a0[kk][j]) * scj + shj, 0.f);
                    float f1 = fmaxf(bf2f((unsigned short)a1[kk][j]) * scj + shj, 0.f);
                    a0[kk][j] = (short)f2bf(f0);
                    a1[kk][j] = (short)f2bf(f1);
                }
            }
        }

        floatx4 acc[2][8] = {};
        #pragma unroll
        for (int kk = 0; kk < 4; ++kk) {
            int cp = (kk * 4 + q) ^ sw;
            #pragma unroll
            for (int c = 0; c < 8; ++c) {
                int nr = c * 16 + m;
                short8 b = *(const short8*)&sB[nr * 128 + (cp << 3)];
                acc[0][c] = __builtin_amdgcn_mfma_f32_16x16x32_bf16(b, a0[kk], acc[0][c], 0, 0, 0);
                acc[1][c] = __builtin_amdgcn_mfma_f32_16x16x32_bf16(b, a1[kk], acc[1][c], 0, 0, 0);
            }
        }

        int r0 = tile * 128;
        #pragma unroll
        for (int c = 0; c < 8; ++c) {
            int ch0 = c * 16 + q * 4;
            float4 bv = *(const float4*)(bias + ch0);
            float sr[4] = {0,0,0,0}, qr[4] = {0,0,0,0};
            #pragma unroll
            for (int h = 0; h < 2; ++h) {
                int node = r0 + w * 32 + h * 16 + m;
                float v0 = acc[h][c][0] + bv.x;
                float v1 = acc[h][c][1] + bv.y;
                float v2 = acc[h][c][2] + bv.z;
                float v3 = acc[h][c][3] + bv.w;
                if (RELU_ST) {
                    v0 = fmaxf(v0, 0.f); v1 = fmaxf(v1, 0.f);
                    v2 = fmaxf(v2, 0.f); v3 = fmaxf(v3, 0.f);
                }
                if (node < N_NODES) {
                    ushort4 o;
                    o.x = f2bf(v0); o.y = f2bf(v1); o.z = f2bf(v2); o.w = f2bf(v3);
                    if (SHARD_OUT) {
                        // shard = c, quad within shard = q
                        *(ushort4*)(Out + (size_t)c * (N_NODES * 16) + (size_t)node * 16 + q * 4) = o;
                    } else {
                        *(ushort4*)(Out + (size_t)node * 128 + ch0) = o;
                    }
                    if (STATS) {
                        sr[0] += v0; sr[1] += v1; sr[2] += v2; sr[3] += v3;
                        qr[0] += v0*v0; qr[1] += v1*v1; qr[2] += v2*v2; qr[3] += v3*v3;
                    }
                }
            }
            if (STATS) {
                #pragma unroll
                for (int msk = 1; msk <= 8; msk <<= 1) {
                    #pragma unroll
                    for (int r = 0; r < 4; ++r) {
                        sr[r] += __shfl_xor(sr[r], msk);
                        qr[r] += __shfl_xor(qr[r], msk);
                    }
                }
                if (m == 0) {
                    #pragma unroll
                    for (int r = 0; r < 4; ++r) {
                        atomicAdd(&s_sum[ch0 + r], sr[r]);
                        atomicAdd(&s_sq [ch0 + r], qr[r]);
                    }
                }
            }
        }

        tile = next;
        if (tile < NTILES) {
            #pragma unroll
            for (int kk = 0; kk < 4; ++kk) { a0[kk] = b0[kk]; a1[kk] = b1[kk]; }
        }
    }

    if (STATS) {
        __syncthreads();
        if (t < 128) {
            atomicAdd(&ssum_out[t], s_sum[t]);
            atomicAdd(&ssq_out [t], s_sq[t]);
        }
    }
}

// ============== Pooling (vectorized: thread = channel-quad x subrow) ==============
#define POOL_BLOCKS 782
#define POOL_CHUNK  128
__global__ __launch_bounds__(256)
void k_pool(const unsigned short* __restrict__ h, const int* __restrict__ batch,
            float* __restrict__ pooled) {
    int t  = threadIdx.x;
    int cq = (t & 31) * 4;      // channel quad base
    int r  = t >> 5;            // subrow 0..7
    int n0 = blockIdx.x * POOL_CHUNK;
    if (n0 >= N_NODES) return;
    int n1 = min(n0 + POOL_CHUNK, N_NODES);
    float a0=0.f, a1=0.f, a2=0.f, a3=0.f;
    int g = -1;
    for (int i = n0 + r; i < n1; i += 8) {
        int gi = batch[i];
        if (gi != g) {
            if (g >= 0) {
                atomicAdd(&pooled[g * DIM + cq + 0], a0);
                atomicAdd(&pooled[g * DIM + cq + 1], a1);
                atomicAdd(&pooled[g * DIM + cq + 2], a2);
                atomicAdd(&pooled[g * DIM + cq + 3], a3);
            }
            a0 = a1 = a2 = a3 = 0.f; g = gi;
        }
        ushort4 v = *(const ushort4*)(h + (size_t)i * DIM + cq);
        a0 += bf2f(v.x); a1 += bf2f(v.y); a2 += bf2f(v.z); a3 += bf2f(v.w);
    }
    if (g >= 0) {
        atomicAdd(&pooled[g * DIM + cq + 0], a0);
        atomicAdd(&pooled[g * DIM + cq + 1], a1);
        atomicAdd(&pooled[g * DIM + cq + 2], a2);
        atomicAdd(&pooled[g * DIM + cq + 3], a3);
    }
}

// ============================ Readout (fused) ============================
__global__ void k_readout(const float* __restrict__ pooled,
                          const float* __restrict__ Wl1, const float* __restrict__ bl1,
                          const float* __restrict__ Wl2, const float* __restrict__ bl2,
                          float* __restrict__ out) {
    __shared__ float p[128], r[128];
    int g = blockIdx.x, c = threadIdx.x;
    p[c] = pooled[g * DIM + c];
    __syncthreads();
    float s = bl1[c];
    #pragma unroll 8
    for (int k = 0; k < DIM; ++k) s += p[k] * Wl1[k * DIM + c];
    r[c] = fmaxf(s, 0.f);
    __syncthreads();
    if (c < OUT_CH) {
        float s2 = bl2[c];
        #pragma unroll 8
        for (int k = 0; k < DIM; ++k) s2 += r[k] * Wl2[k * OUT_CH + c];
        out[g * OUT_CH + c] = s2;
    }
}

// ============================ Launch ============================
extern "C" void kernel_launch(void* const* d_in, const int* in_sizes, int n_in,
                              void* d_out, int out_size, void* d_ws, size_t ws_size,
                              hipStream_t stream) {
    const float* x   = (const float*)d_in[0];
    const int*   ei  = (const int*)d_in[1];
    const int*   bat = (const int*)d_in[2];
    const float* W1a = (const float*)d_in[3];
    const float* b1a = (const float*)d_in[4];
    const float* ga  = (const float*)d_in[5];
    const float* ba  = (const float*)d_in[6];
    const float* W2a = (const float*)d_in[7];
    const float* b2a = (const float*)d_in[8];
    const float* W1b = (const float*)d_in[9];
    const float* b1b = (const float*)d_in[10];
    const float* gb  = (const float*)d_in[11];
    const float* bbt = (const float*)d_in[12];
    const float* W2b = (const float*)d_in[13];
    const float* b2b = (const float*)d_in[14];
    const float* Wl1 = (const float*)d_in[15];
    const float* bl1 = (const float*)d_in[16];
    const float* Wl2 = (const float*)d_in[17];
    const float* bl2 = (const float*)d_in[18];
    float* out = (float*)d_out;

    const int* src = ei;
    const int* dst = ei + N_EDGES;

    char* w = (char*)d_ws;
    size_t off = 0;
    auto alloc = [&](size_t bytes) -> char* {
        char* p = w + off; off += (bytes + 255) & ~(size_t)255; return p;
    };
    unsigned short* xb   = (unsigned short*)alloc((size_t)N_NODES * DIM * 2);
    unsigned short* nb0  = (unsigned short*)alloc((size_t)N_NODES * DIM * 2);
    unsigned short* nb1  = (unsigned short*)alloc((size_t)N_NODES * DIM * 2);
    unsigned short* Wtb  = (unsigned short*)alloc((size_t)4 * DIM * DIM * 2);
    unsigned* pairs = (unsigned*)alloc((size_t)NB2 * CAP2 * 4);
    int*   row_ptr = (int*)  alloc((size_t)(N_NODES + 1) * 4);
    int*   col     = (int*)  alloc((size_t)N_EDGES * 4);
    int*   gcur    = (int*)  alloc((NB2 + 1) * 4);
    int*   bbase   = (int*)  alloc((NB2 + 1) * 4);
    float* stats4  = (float*)alloc((size_t)4 * DIM * 4);
    float* pooled  = (float*)alloc((size_t)NUM_GRAPHS * DIM * 4);
    float* ssumA = stats4, *ssqA = stats4 + DIM, *ssumB = stats4 + 2*DIM, *ssqB = stats4 + 3*DIM;

    k_cvt_x<<<(N_NODES * DIM / 4) / 256, 256, 0, stream>>>(x, xb, gcur, stats4, pooled);
    k_prep_w<<<dim3(64, 4), 256, 0, stream>>>(W1a, W2a, W1b, W2b, Wtb);
    const unsigned short* Wt1a = Wtb;
    const unsigned short* Wt2a = Wtb + DIM * DIM;
    const unsigned short* Wt1b = Wtb + 2 * DIM * DIM;
    const unsigned short* Wt2b = Wtb + 3 * DIM * DIM;

    k_bucket<<<(N_EDGES + 8191) / 8192, 256, 0, stream>>>(src, dst, gcur, pairs);
    k_bscan<<<1, 512, 0, stream>>>(gcur, bbase, row_ptr);
    k_csr<<<NB2, 256, 0, stream>>>(pairs, gcur, bbase, row_ptr, col);

    // conv1
    k_agg<<<AGG_BLOCKS, 256, 0, stream>>>(xb, nb0, row_ptr, col);
    k_gemm<false, true, false, false><<<GEMM_GRID, 256, 0, stream>>>(
        nb0, nb1, Wt1a, b1a, nullptr, nullptr, nullptr, nullptr, ssumA, ssqA);
    k_gemm<true, false, true, true><<<GEMM_GRID, 256, 0, stream>>>(
        nb1, nb0, Wt2a, b2a, ssumA, ssqA, ga, ba, nullptr, nullptr);
    // conv2 (nb0 is shard-major here)
    k_agg<<<AGG_BLOCKS, 256, 0, stream>>>(nb0, nb1, row_ptr, col);
    k_gemm<false, true, false, false><<<GEMM_GRID, 256, 0, stream>>>(
        nb1, nb0, Wt1b, b1b, nullptr, nullptr, nullptr, nullptr, ssumB, ssqB);
    k_gemm<true, false, true, false><<<GEMM_GRID, 256, 0, stream>>>(
        nb0, nb1, Wt2b, b2b, ssumB, ssqB, gb, bbt, nullptr, nullptr);
    // readout
    k_pool<<<POOL_BLOCKS, 256, 0, stream>>>(nb1, bat, pooled);
    k_readout<<<NUM_GRAPHS, 128, 0, stream>>>(pooled, Wl1, bl1, Wl2, bl2, out);
}